// Round 1
// baseline (818.688 us; speedup 1.0000x reference)
//
#include <hip/hip_runtime.h>
#include <hip/hip_bf16.h>

#define N_NODES 50000
#define N_EDGES 500000

// ---------------- CSR build ----------------

__global__ void hist_kernel(const int* __restrict__ dst, int* __restrict__ deg, int nE) {
    int e = blockIdx.x * 256 + threadIdx.x;
    if (e < nE) atomicAdd(&deg[dst[e]], 1);
}

// degcur holds degrees on entry; on exit degcur[i] = row start (cursor), off = offsets
__global__ void scan_kernel(int* __restrict__ degcur, int* __restrict__ off, int n) {
    __shared__ int sdata[1024];
    __shared__ int carry;
    int tid = threadIdx.x;
    if (tid == 0) { carry = 0; off[0] = 0; }
    __syncthreads();
    for (int base = 0; base < n; base += 1024) {
        int i = base + tid;
        int v = (i < n) ? degcur[i] : 0;
        sdata[tid] = v;
        __syncthreads();
        #pragma unroll
        for (int d = 1; d < 1024; d <<= 1) {
            int t = (tid >= d) ? sdata[tid - d] : 0;
            __syncthreads();
            sdata[tid] += t;
            __syncthreads();
        }
        int inc = sdata[tid];
        int c = carry;
        int total = sdata[1023];
        __syncthreads();
        if (i < n) { off[i + 1] = c + inc; degcur[i] = c + inc - v; }
        if (tid == 0) carry = c + total;
        __syncthreads();
    }
}

__global__ void fill_kernel(const int* __restrict__ src, const int* __restrict__ dst,
                            int* __restrict__ cur, int* __restrict__ csr, int nE) {
    int e = blockIdx.x * 256 + threadIdx.x;
    if (e < nE) {
        int p = atomicAdd(&cur[dst[e]], 1);
        csr[p] = src[e];
    }
}

// ---------------- Aggregation (gather via CSR) ----------------

template<int F>
__global__ __launch_bounds__(256) void agg_kernel(const float* __restrict__ h,
                                                  const int* __restrict__ off,
                                                  const int* __restrict__ csr,
                                                  float* __restrict__ outp, int nNodes) {
    constexpr int NPB = 256 / F;  // nodes per block
    int node = blockIdx.x * NPB + threadIdx.x / F;
    int f = threadIdx.x % F;
    if (node >= nNodes) return;
    int s = off[node], e = off[node + 1];
    float acc = 0.f;
    for (int i = s; i < e; ++i) {
        int sn = csr[i];
        acc += h[(size_t)sn * F + f];
    }
    outp[(size_t)node * F + f] = acc;
}

// ---------------- fp32 tiled GEMM, fused bias+relu ----------------
// C[M,N] = A[M,K] @ B[K,N] (+bias) (relu). K % 16 == 0, N % 64 == 0.

#define GBM 64
#define GBN 64
#define GBK 16

__global__ __launch_bounds__(256) void gemm_kernel(const float* __restrict__ A,
                                                   const float* __restrict__ B,
                                                   const float* __restrict__ bias,
                                                   float* __restrict__ C,
                                                   int M, int K, int N, int doRelu) {
    __shared__ float As[GBK][GBM + 4];   // +4 keeps float4 alignment (stride 272B)
    __shared__ float Bs[GBK][GBN + 4];
    int tid = threadIdx.x;
    int m0 = blockIdx.y * GBM;
    int n0 = blockIdx.x * GBN;
    int tm = (tid >> 4) << 2;
    int tn = (tid & 15) << 2;
    int lam = tid >> 2;            // 0..63  (A row within tile)
    int lak = (tid & 3) << 2;      // 0,4,8,12 (A k within tile)
    int lbk = tid >> 4;            // 0..15  (B k within tile)
    int lbn = (tid & 15) << 2;     // B col within tile
    float acc[4][4] = {{0.f}};
    for (int k0 = 0; k0 < K; k0 += GBK) {
        float4 av;
        int ar = m0 + lam;
        if (ar < M) av = *(const float4*)(A + (size_t)ar * K + k0 + lak);
        else        av = make_float4(0.f, 0.f, 0.f, 0.f);
        float4 bv = *(const float4*)(B + (size_t)(k0 + lbk) * N + n0 + lbn);
        As[lak + 0][lam] = av.x;
        As[lak + 1][lam] = av.y;
        As[lak + 2][lam] = av.z;
        As[lak + 3][lam] = av.w;
        *(float4*)&Bs[lbk][lbn] = bv;
        __syncthreads();
        #pragma unroll
        for (int k = 0; k < GBK; ++k) {
            float4 a = *(const float4*)&As[k][tm];
            float4 b = *(const float4*)&Bs[k][tn];
            float aa[4] = {a.x, a.y, a.z, a.w};
            float bb[4] = {b.x, b.y, b.z, b.w};
            #pragma unroll
            for (int i = 0; i < 4; ++i)
                #pragma unroll
                for (int j = 0; j < 4; ++j)
                    acc[i][j] += aa[i] * bb[j];
        }
        __syncthreads();
    }
    #pragma unroll
    for (int i = 0; i < 4; ++i) {
        int row = m0 + tm + i;
        if (row >= M) continue;
        #pragma unroll
        for (int j = 0; j < 4; ++j) {
            int col = n0 + tn + j;
            float v = acc[i][j];
            if (bias) v += bias[col];
            if (doRelu) v = fmaxf(v, 0.f);
            C[(size_t)row * N + col] = v;
        }
    }
}

// ---------------- final relu + column mean ----------------
// out[f] = mean_n relu(t[n,f] + b3[f])

__global__ __launch_bounds__(256) void mean_kernel(const float* __restrict__ t,
                                                   const float* __restrict__ b3,
                                                   float* __restrict__ outp, int nNodes) {
    __shared__ float s[256];
    int f = threadIdx.x & 127;
    int half = threadIdx.x >> 7;
    float bias = b3[f];
    float acc = 0.f;
    int r0 = blockIdx.x * 256;
    int rEnd = r0 + 256 < nNodes ? r0 + 256 : nNodes;
    for (int r = r0 + half; r < rEnd; r += 2) {
        float v = t[(size_t)r * 128 + f] + bias;
        acc += fmaxf(v, 0.f);
    }
    s[threadIdx.x] = acc;
    __syncthreads();
    if (half == 0) atomicAdd(&outp[f], (s[f] + s[f + 128]) * (1.0f / nNodes));
}

// ---------------- launch ----------------

extern "C" void kernel_launch(void* const* d_in, const int* in_sizes, int n_in,
                              void* d_out, int out_size, void* d_ws, size_t ws_size,
                              hipStream_t stream) {
    const float* x  = (const float*)d_in[0];
    const int*   src = (const int*)d_in[1];
    const int*   dst = (const int*)d_in[2];
    const float* W1 = (const float*)d_in[3];
    const float* b1 = (const float*)d_in[4];
    const float* W2 = (const float*)d_in[5];
    const float* b2 = (const float*)d_in[6];
    const float* W3 = (const float*)d_in[7];
    const float* b3 = (const float*)d_in[8];
    float* out = (float*)d_out;

    char* ws = (char*)d_ws;
    size_t o = 0;
    auto alloc = [&](size_t bytes) -> char* {
        char* p = ws + o;
        o = (o + bytes + 255) & ~(size_t)255;
        return p;
    };
    int*   off  = (int*)alloc((size_t)(N_NODES + 1) * 4);
    int*   cur  = (int*)alloc((size_t)N_NODES * 4);
    int*   csr  = (int*)alloc((size_t)N_EDGES * 4);
    float* bufA = (float*)alloc((size_t)N_NODES * 256 * 4);
    float* bufB = (float*)alloc((size_t)N_NODES * 256 * 4);

    // CSR build (rebuilt every call; ws is re-poisoned by the harness)
    hipMemsetAsync(cur, 0, (size_t)N_NODES * 4, stream);
    hist_kernel<<<(N_EDGES + 255) / 256, 256, 0, stream>>>(dst, cur, N_EDGES);
    scan_kernel<<<1, 1024, 0, stream>>>(cur, off, N_NODES);
    fill_kernel<<<(N_EDGES + 255) / 256, 256, 0, stream>>>(src, dst, cur, csr, N_EDGES);

    const int mb = (N_NODES + GBM - 1) / GBM;  // 782

    // Layer 1: agg(x) @ W1 + b1, relu
    agg_kernel<128><<<(N_NODES + 1) / 2, 256, 0, stream>>>(x, off, csr, bufA, N_NODES);
    gemm_kernel<<<dim3(256 / GBN, mb), 256, 0, stream>>>(bufA, W1, b1, bufB,
                                                         N_NODES, 128, 256, 1);
    // Layer 2: agg(h1) @ W2 + b2, relu
    agg_kernel<256><<<N_NODES, 256, 0, stream>>>(bufB, off, csr, bufA, N_NODES);
    gemm_kernel<<<dim3(256 / GBN, mb), 256, 0, stream>>>(bufA, W2, b2, bufB,
                                                         N_NODES, 256, 256, 1);
    // Layer 3 reordered: t = h2 @ W3 (no bias), agg3 = segsum(t), out = mean(relu(agg3 + b3))
    gemm_kernel<<<dim3(128 / GBN, mb), 256, 0, stream>>>(bufB, W3, nullptr, bufA,
                                                         N_NODES, 256, 128, 0);
    agg_kernel<128><<<(N_NODES + 1) / 2, 256, 0, stream>>>(bufA, off, csr, bufB, N_NODES);

    hipMemsetAsync(out, 0, 128 * 4, stream);
    mean_kernel<<<(N_NODES + 255) / 256, 256, 0, stream>>>(bufB, b3, out, N_NODES);
}

// Round 2
// 374.968 us; speedup vs baseline: 2.1834x; 2.1834x over previous
//
#include <hip/hip_runtime.h>

#define N_NODES 50000
#define N_EDGES 500000

typedef __attribute__((ext_vector_type(8))) short short8;
typedef __attribute__((ext_vector_type(4))) float floatx4;

__device__ inline float bf2f(unsigned short u) {
    unsigned int x = ((unsigned int)u) << 16;
    return __builtin_bit_cast(float, x);
}
__device__ inline unsigned short f2bf(float f) {  // round-to-nearest-even
    unsigned int x = __builtin_bit_cast(unsigned int, f);
    x += 0x7fff + ((x >> 16) & 1);
    return (unsigned short)(x >> 16);
}

// ---------------- CSR build ----------------

__global__ void hist_kernel(const int* __restrict__ dst, int* __restrict__ deg, int nE) {
    int e = blockIdx.x * 256 + threadIdx.x;
    if (e < nE) atomicAdd(&deg[dst[e]], 1);
}

__global__ void scan_block_kernel(const int* __restrict__ deg, int* __restrict__ partial,
                                  int* __restrict__ bsum, int n) {
    __shared__ int s[256];
    int i = blockIdx.x * 256 + threadIdx.x;
    int v = (i < n) ? deg[i] : 0;
    s[threadIdx.x] = v;
    __syncthreads();
    #pragma unroll
    for (int d = 1; d < 256; d <<= 1) {
        int t = (threadIdx.x >= d) ? s[threadIdx.x - d] : 0;
        __syncthreads();
        s[threadIdx.x] += t;
        __syncthreads();
    }
    if (i < n) partial[i] = s[threadIdx.x];
    if (threadIdx.x == 255) bsum[blockIdx.x] = s[255];
}

__global__ void scan_bsum_kernel(int* __restrict__ bsum, int nb) {
    __shared__ int s[256];
    int t = threadIdx.x;
    int v = (t < nb) ? bsum[t] : 0;
    s[t] = v;
    __syncthreads();
    #pragma unroll
    for (int d = 1; d < 256; d <<= 1) {
        int u = (t >= d) ? s[t - d] : 0;
        __syncthreads();
        s[t] += u;
        __syncthreads();
    }
    if (t < nb) bsum[t] = s[t];
}

// cur holds deg on entry; exit: cur = row start, off = offsets
__global__ void finalize_kernel(const int* __restrict__ partial, const int* __restrict__ bsum,
                                int* __restrict__ cur, int* __restrict__ off, int n) {
    int i = blockIdx.x * 256 + threadIdx.x;
    if (i == 0) off[0] = 0;
    if (i < n) {
        int base = (blockIdx.x > 0) ? bsum[blockIdx.x - 1] : 0;
        int incl = base + partial[i];
        off[i + 1] = incl;
        cur[i] = incl - cur[i];
    }
}

__global__ void fill_kernel(const int* __restrict__ src, const int* __restrict__ dst,
                            int* __restrict__ cur, int* __restrict__ csr, int nE) {
    int e = blockIdx.x * 256 + threadIdx.x;
    if (e < nE) {
        int p = atomicAdd(&cur[dst[e]], 1);
        csr[p] = src[e];
    }
}

// ---------------- dtype conversion ----------------

__global__ void f2bf_kernel(const float* __restrict__ in, unsigned short* __restrict__ outp, int n) {
    int i = (blockIdx.x * 256 + threadIdx.x) * 4;
    if (i < n) {
        float4 v = *(const float4*)(in + i);
        ushort4 o;
        o.x = f2bf(v.x); o.y = f2bf(v.y); o.z = f2bf(v.z); o.w = f2bf(v.w);
        *(ushort4*)(outp + i) = o;
    }
}

// Wt[n*K+k] = bf16(W[k*N+n])
__global__ void transpose_bf_kernel(const float* __restrict__ W, unsigned short* __restrict__ Wt,
                                    int K, int N) {
    int idx = blockIdx.x * 256 + threadIdx.x;
    if (idx < K * N) {
        int k = idx / N, n = idx % N;
        Wt[n * K + k] = f2bf(W[idx]);
    }
}

// ---------------- Aggregation: one wave per node, unroll-4 edge loop ----------------

template<int F>  // F=128: lane handles 2 feats; F=256: 4 feats
__global__ __launch_bounds__(256) void agg_bf_kernel(const unsigned short* __restrict__ h,
                                                     const int* __restrict__ off,
                                                     const int* __restrict__ csr,
                                                     unsigned short* __restrict__ outp, int nNodes) {
    constexpr int VEC = F / 64;
    int node = blockIdx.x * 4 + (threadIdx.x >> 6);
    if (node >= nNodes) return;
    int lane = threadIdx.x & 63;
    int f0 = lane * VEC;
    int s = off[node], e = off[node + 1];
    float acc[VEC];
    #pragma unroll
    for (int v = 0; v < VEC; v++) acc[v] = 0.f;
    int i = s;
    for (; i + 4 <= e; i += 4) {
        int n0 = csr[i], n1 = csr[i + 1], n2 = csr[i + 2], n3 = csr[i + 3];
        if (VEC == 4) {
            ushort4 a = *(const ushort4*)(h + (size_t)n0 * F + f0);
            ushort4 b = *(const ushort4*)(h + (size_t)n1 * F + f0);
            ushort4 c = *(const ushort4*)(h + (size_t)n2 * F + f0);
            ushort4 d = *(const ushort4*)(h + (size_t)n3 * F + f0);
            acc[0] += bf2f(a.x) + bf2f(b.x) + bf2f(c.x) + bf2f(d.x);
            acc[1] += bf2f(a.y) + bf2f(b.y) + bf2f(c.y) + bf2f(d.y);
            acc[2] += bf2f(a.z) + bf2f(b.z) + bf2f(c.z) + bf2f(d.z);
            acc[3] += bf2f(a.w) + bf2f(b.w) + bf2f(c.w) + bf2f(d.w);
        } else {
            ushort2 a = *(const ushort2*)(h + (size_t)n0 * F + f0);
            ushort2 b = *(const ushort2*)(h + (size_t)n1 * F + f0);
            ushort2 c = *(const ushort2*)(h + (size_t)n2 * F + f0);
            ushort2 d = *(const ushort2*)(h + (size_t)n3 * F + f0);
            acc[0] += bf2f(a.x) + bf2f(b.x) + bf2f(c.x) + bf2f(d.x);
            acc[1] += bf2f(a.y) + bf2f(b.y) + bf2f(c.y) + bf2f(d.y);
        }
    }
    for (; i < e; ++i) {
        int n0 = csr[i];
        if (VEC == 4) {
            ushort4 a = *(const ushort4*)(h + (size_t)n0 * F + f0);
            acc[0] += bf2f(a.x); acc[1] += bf2f(a.y); acc[2] += bf2f(a.z); acc[3] += bf2f(a.w);
        } else {
            ushort2 a = *(const ushort2*)(h + (size_t)n0 * F + f0);
            acc[0] += bf2f(a.x); acc[1] += bf2f(a.y);
        }
    }
    if (VEC == 4) {
        ushort4 o;
        o.x = f2bf(acc[0]); o.y = f2bf(acc[1]); o.z = f2bf(acc[2]); o.w = f2bf(acc[3]);
        *(ushort4*)(outp + (size_t)node * F + f0) = o;
    } else {
        ushort2 o;
        o.x = f2bf(acc[0]); o.y = f2bf(acc[1]);
        *(ushort2*)(outp + (size_t)node * F + f0) = o;
    }
}

// fp32 in/out, F=128 (layer-3 aggregation of t)
__global__ __launch_bounds__(256) void agg_f32_kernel(const float* __restrict__ h,
                                                      const int* __restrict__ off,
                                                      const int* __restrict__ csr,
                                                      float* __restrict__ outp, int nNodes) {
    int node = blockIdx.x * 4 + (threadIdx.x >> 6);
    if (node >= nNodes) return;
    int lane = threadIdx.x & 63;
    int f0 = lane * 2;
    int s = off[node], e = off[node + 1];
    float a0 = 0.f, a1 = 0.f;
    int i = s;
    for (; i + 4 <= e; i += 4) {
        int n0 = csr[i], n1 = csr[i + 1], n2 = csr[i + 2], n3 = csr[i + 3];
        float2 a = *(const float2*)(h + (size_t)n0 * 128 + f0);
        float2 b = *(const float2*)(h + (size_t)n1 * 128 + f0);
        float2 c = *(const float2*)(h + (size_t)n2 * 128 + f0);
        float2 d = *(const float2*)(h + (size_t)n3 * 128 + f0);
        a0 += a.x + b.x + c.x + d.x;
        a1 += a.y + b.y + c.y + d.y;
    }
    for (; i < e; ++i) {
        float2 a = *(const float2*)(h + (size_t)csr[i] * 128 + f0);
        a0 += a.x; a1 += a.y;
    }
    float2 o; o.x = a0; o.y = a1;
    *(float2*)(outp + (size_t)node * 128 + f0) = o;
}

// ---------------- bf16 MFMA GEMM ----------------
// C[M,N] = A[M,K] @ B[K,N] (+bias) (relu). A: bf16 MxK. Bt: bf16 NxK (pre-transposed).
// Block 256 thr = 4 waves (2x2), tile 128x128x32, each wave 64x64 via 4x4 mfma 16x16x32.

template<typename T> __device__ inline void storeC(T* p, float v);
template<> __device__ inline void storeC<float>(float* p, float v) { *p = v; }
template<> __device__ inline void storeC<unsigned short>(unsigned short* p, float v) { *p = f2bf(v); }

template<typename OUT_T>
__global__ __launch_bounds__(256) void gemm_bf16_kernel(const unsigned short* __restrict__ A,
                                                        const unsigned short* __restrict__ Bt,
                                                        const float* __restrict__ bias,
                                                        OUT_T* __restrict__ C,
                                                        int M, int K, int N, int doRelu) {
    constexpr int BM = 128, BN = 128, BK = 32, LDA = BK + 8;  // pad 8 shorts -> 80B row stride
    __shared__ unsigned short As[BM * LDA];
    __shared__ unsigned short Bs[BN * LDA];
    int tid = threadIdx.x;
    int m0 = blockIdx.y * BM, n0 = blockIdx.x * BN;
    int wave = tid >> 6, lane = tid & 63;
    int wm = wave >> 1, wn = wave & 1;
    int mlane = lane & 15, kgrp = lane >> 4;

    floatx4 acc[4][4];
    #pragma unroll
    for (int i = 0; i < 4; i++)
        #pragma unroll
        for (int j = 0; j < 4; j++) acc[i][j] = (floatx4){0.f, 0.f, 0.f, 0.f};

    for (int k0 = 0; k0 < K; k0 += BK) {
        #pragma unroll
        for (int it = 0; it < 2; ++it) {
            int c = tid + it * 256;         // 0..511
            int r = c >> 2, cb = (c & 3) * 8;
            int rg = m0 + r;
            short8 v;
            if (rg < M) v = *(const short8*)(A + (size_t)rg * K + k0 + cb);
            else        v = (short8){0, 0, 0, 0, 0, 0, 0, 0};
            *(short8*)&As[r * LDA + cb] = v;
            short8 w = *(const short8*)(Bt + (size_t)(n0 + r) * K + k0 + cb);
            *(short8*)&Bs[r * LDA + cb] = w;
        }
        __syncthreads();
        short8 af[4], bfr[4];
        #pragma unroll
        for (int mt = 0; mt < 4; mt++)
            af[mt] = *(const short8*)&As[(wm * 64 + mt * 16 + mlane) * LDA + kgrp * 8];
        #pragma unroll
        for (int nt = 0; nt < 4; nt++)
            bfr[nt] = *(const short8*)&Bs[(wn * 64 + nt * 16 + mlane) * LDA + kgrp * 8];
        #pragma unroll
        for (int mt = 0; mt < 4; mt++)
            #pragma unroll
            for (int nt = 0; nt < 4; nt++)
                acc[mt][nt] = __builtin_amdgcn_mfma_f32_16x16x32_bf16(af[mt], bfr[nt],
                                                                      acc[mt][nt], 0, 0, 0);
        __syncthreads();
    }
    // epilogue: D row=(lane>>4)*4+r, col=lane&15 within each 16x16 tile
    #pragma unroll
    for (int mt = 0; mt < 4; mt++) {
        #pragma unroll
        for (int nt = 0; nt < 4; nt++) {
            int col = n0 + wn * 64 + nt * 16 + mlane;
            float bv = bias ? bias[col] : 0.f;
            #pragma unroll
            for (int r = 0; r < 4; r++) {
                int row = m0 + wm * 64 + mt * 16 + kgrp * 4 + r;
                if (row < M) {
                    float v = acc[mt][nt][r] + bv;
                    if (doRelu) v = fmaxf(v, 0.f);
                    storeC(C + (size_t)row * N + col, v);
                }
            }
        }
    }
}

// ---------------- final relu + column mean ----------------

__global__ __launch_bounds__(256) void mean_kernel(const float* __restrict__ t,
                                                   const float* __restrict__ b3,
                                                   float* __restrict__ outp, int nNodes) {
    __shared__ float s[256];
    int f = threadIdx.x & 127;
    int half = threadIdx.x >> 7;
    float bias = b3[f];
    float acc = 0.f;
    int r0 = blockIdx.x * 256;
    int rEnd = r0 + 256 < nNodes ? r0 + 256 : nNodes;
    for (int r = r0 + half; r < rEnd; r += 2) {
        float v = t[(size_t)r * 128 + f] + bias;
        acc += fmaxf(v, 0.f);
    }
    s[threadIdx.x] = acc;
    __syncthreads();
    if (half == 0) atomicAdd(&outp[f], (s[f] + s[f + 128]) * (1.0f / nNodes));
}

// ---------------- launch ----------------

extern "C" void kernel_launch(void* const* d_in, const int* in_sizes, int n_in,
                              void* d_out, int out_size, void* d_ws, size_t ws_size,
                              hipStream_t stream) {
    const float* x   = (const float*)d_in[0];
    const int*   src = (const int*)d_in[1];
    const int*   dst = (const int*)d_in[2];
    const float* W1 = (const float*)d_in[3];
    const float* b1 = (const float*)d_in[4];
    const float* W2 = (const float*)d_in[5];
    const float* b2 = (const float*)d_in[6];
    const float* W3 = (const float*)d_in[7];
    const float* b3 = (const float*)d_in[8];
    float* out = (float*)d_out;

    char* ws = (char*)d_ws;
    size_t o = 0;
    auto alloc = [&](size_t bytes) -> char* {
        char* p = ws + o;
        o = (o + bytes + 255) & ~(size_t)255;
        return p;
    };
    int* off     = (int*)alloc((size_t)(N_NODES + 1) * 4);
    int* cur     = (int*)alloc((size_t)N_NODES * 4);
    int* csr     = (int*)alloc((size_t)N_EDGES * 4);
    int* partial = (int*)alloc((size_t)N_NODES * 4);
    int* bsum    = (int*)alloc(256 * 4);
    unsigned short* Wt1 = (unsigned short*)alloc((size_t)128 * 256 * 2);
    unsigned short* Wt2 = (unsigned short*)alloc((size_t)256 * 256 * 2);
    unsigned short* Wt3 = (unsigned short*)alloc((size_t)256 * 128 * 2);
    char* R1 = alloc((size_t)N_NODES * 256 * 2);  // 25.6 MB
    char* R2 = alloc((size_t)N_NODES * 256 * 2);
    char* R3 = alloc((size_t)N_NODES * 128 * 4);  // 25.6 MB (fp32 x 128 capable)

    unsigned short* xb    = (unsigned short*)R1;  // 50000x128 bf16
    unsigned short* aggX  = (unsigned short*)R2;  // 50000x128 bf16
    unsigned short* h1    = (unsigned short*)R3;  // 50000x256 bf16
    unsigned short* agg2o = (unsigned short*)R1;  // 50000x256 bf16
    unsigned short* h2    = (unsigned short*)R2;  // 50000x256 bf16
    float*          t     = (float*)R3;           // 50000x128 fp32
    float*          agg3o = (float*)R1;           // 50000x128 fp32

    const int nb = (N_NODES + 255) / 256;  // 196

    // CSR build
    hipMemsetAsync(cur, 0, (size_t)N_NODES * 4, stream);
    hist_kernel<<<(N_EDGES + 255) / 256, 256, 0, stream>>>(dst, cur, N_EDGES);
    scan_block_kernel<<<nb, 256, 0, stream>>>(cur, partial, bsum, N_NODES);
    scan_bsum_kernel<<<1, 256, 0, stream>>>(bsum, nb);
    finalize_kernel<<<nb, 256, 0, stream>>>(partial, bsum, cur, off, N_NODES);
    fill_kernel<<<(N_EDGES + 255) / 256, 256, 0, stream>>>(src, dst, cur, csr, N_EDGES);

    // weights -> bf16 transposed [N][K]; x -> bf16
    transpose_bf_kernel<<<(128 * 256 + 255) / 256, 256, 0, stream>>>(W1, Wt1, 128, 256);
    transpose_bf_kernel<<<(256 * 256 + 255) / 256, 256, 0, stream>>>(W2, Wt2, 256, 256);
    transpose_bf_kernel<<<(256 * 128 + 255) / 256, 256, 0, stream>>>(W3, Wt3, 256, 128);
    f2bf_kernel<<<(N_NODES * 128 / 4 + 255) / 256, 256, 0, stream>>>(x, xb, N_NODES * 128);

    const int aggGrid = (N_NODES + 3) / 4;
    const int mb = (N_NODES + 127) / 128;  // 391

    // Layer 1
    agg_bf_kernel<128><<<aggGrid, 256, 0, stream>>>(xb, off, csr, aggX, N_NODES);
    gemm_bf16_kernel<unsigned short><<<dim3(2, mb), 256, 0, stream>>>(aggX, Wt1, b1, h1,
                                                                      N_NODES, 128, 256, 1);
    // Layer 2
    agg_bf_kernel<256><<<aggGrid, 256, 0, stream>>>(h1, off, csr, agg2o, N_NODES);
    gemm_bf16_kernel<unsigned short><<<dim3(2, mb), 256, 0, stream>>>(agg2o, Wt2, b2, h2,
                                                                      N_NODES, 256, 256, 1);
    // Layer 3 reordered: t = h2 @ W3 (fp32 out), agg3 = segsum(t), out = mean(relu(agg3 + b3))
    gemm_bf16_kernel<float><<<dim3(1, mb), 256, 0, stream>>>(h2, Wt3, nullptr, t,
                                                             N_NODES, 256, 128, 0);
    agg_f32_kernel<<<aggGrid, 256, 0, stream>>>(t, off, csr, agg3o, N_NODES);

    hipMemsetAsync(out, 0, 128 * 4, stream);
    mean_kernel<<<(N_NODES + 255) / 256, 256, 0, stream>>>(agg3o, b3, out, N_NODES);
}

// Round 3
// 358.849 us; speedup vs baseline: 2.2814x; 1.0449x over previous
//
#include <hip/hip_runtime.h>

#define N_NODES 50000
#define N_EDGES 500000

typedef __attribute__((ext_vector_type(8))) short short8;
typedef __attribute__((ext_vector_type(4))) float floatx4;

__device__ inline float bf2f(unsigned short u) {
    unsigned int x = ((unsigned int)u) << 16;
    return __builtin_bit_cast(float, x);
}
__device__ inline unsigned short f2bf(float f) {  // round-to-nearest-even
    unsigned int x = __builtin_bit_cast(unsigned int, f);
    x += 0x7fff + ((x >> 16) & 1);
    return (unsigned short)(x >> 16);
}

// ---------------- CSR build ----------------

__global__ void hist_kernel(const int* __restrict__ dst, int* __restrict__ deg, int nE) {
    int e = blockIdx.x * 256 + threadIdx.x;
    if (e < nE) atomicAdd(&deg[dst[e]], 1);
}

__global__ void scan_block_kernel(const int* __restrict__ deg, int* __restrict__ partial,
                                  int* __restrict__ bsum, int n) {
    __shared__ int s[256];
    int i = blockIdx.x * 256 + threadIdx.x;
    int v = (i < n) ? deg[i] : 0;
    s[threadIdx.x] = v;
    __syncthreads();
    #pragma unroll
    for (int d = 1; d < 256; d <<= 1) {
        int t = (threadIdx.x >= d) ? s[threadIdx.x - d] : 0;
        __syncthreads();
        s[threadIdx.x] += t;
        __syncthreads();
    }
    if (i < n) partial[i] = s[threadIdx.x];
    if (threadIdx.x == 255) bsum[blockIdx.x] = s[255];
}

__global__ void scan_bsum_kernel(int* __restrict__ bsum, int nb) {
    __shared__ int s[256];
    int t = threadIdx.x;
    int v = (t < nb) ? bsum[t] : 0;
    s[t] = v;
    __syncthreads();
    #pragma unroll
    for (int d = 1; d < 256; d <<= 1) {
        int u = (t >= d) ? s[t - d] : 0;
        __syncthreads();
        s[t] += u;
        __syncthreads();
    }
    if (t < nb) bsum[t] = s[t];
}

// cur holds deg on entry; exit: cur = row start, off = offsets
__global__ void finalize_kernel(const int* __restrict__ partial, const int* __restrict__ bsum,
                                int* __restrict__ cur, int* __restrict__ off, int n) {
    int i = blockIdx.x * 256 + threadIdx.x;
    if (i == 0) off[0] = 0;
    if (i < n) {
        int base = (blockIdx.x > 0) ? bsum[blockIdx.x - 1] : 0;
        int incl = base + partial[i];
        off[i + 1] = incl;
        cur[i] = incl - cur[i];
    }
}

__global__ void fill_kernel(const int* __restrict__ src, const int* __restrict__ dst,
                            int* __restrict__ cur, int* __restrict__ csr, int nE) {
    int e = blockIdx.x * 256 + threadIdx.x;
    if (e < nE) {
        int p = atomicAdd(&cur[dst[e]], 1);
        csr[p] = src[e];
    }
}

// ---------------- fused prep: 3 weight transposes (bf16) + x -> bf16 ----------------
// region [0,32768): W1 (128x256) -> Wt1[N][K]
// region [32768,98304): W2 (256x256) -> Wt2
// region [98304,131072): W3 (256x128) -> Wt3
// region [131072,...): x float4 -> bf16 x4

__global__ __launch_bounds__(256) void prep_kernel(const float* __restrict__ W1,
                                                   const float* __restrict__ W2,
                                                   const float* __restrict__ W3,
                                                   const float* __restrict__ x,
                                                   unsigned short* __restrict__ Wt1,
                                                   unsigned short* __restrict__ Wt2,
                                                   unsigned short* __restrict__ Wt3,
                                                   unsigned short* __restrict__ xb) {
    int idx = blockIdx.x * 256 + threadIdx.x;
    if (idx < 32768) {
        int k = idx >> 8, n = idx & 255;
        Wt1[n * 128 + k] = f2bf(W1[idx]);
    } else if (idx < 98304) {
        int i = idx - 32768;
        int k = i >> 8, n = i & 255;
        Wt2[n * 256 + k] = f2bf(W2[i]);
    } else if (idx < 131072) {
        int i = idx - 98304;
        int k = i >> 7, n = i & 127;
        Wt3[n * 256 + k] = f2bf(W3[i]);
    } else {
        int i = (idx - 131072) * 4;
        if (i < N_NODES * 128) {
            float4 v = *(const float4*)(x + i);
            ushort4 o;
            o.x = f2bf(v.x); o.y = f2bf(v.y); o.z = f2bf(v.z); o.w = f2bf(v.w);
            *(ushort4*)(xb + i) = o;
        }
    }
}

// ---------------- Aggregation: bf16 gather, unroll-8 clamped, ushort2/lane ----------------
// F=128: 1 wave/node (4 nodes/block). F=256: 2 waves/node (2 nodes/block).
// Requires N_NODES divisible by nodes-per-block (50000 % 4 == 0, % 2 == 0).

template<int F>
__global__ __launch_bounds__(256) void agg_bf_kernel(const unsigned short* __restrict__ h,
                                                     const int* __restrict__ off,
                                                     const int* __restrict__ csr,
                                                     unsigned short* __restrict__ outp) {
    constexpr int WPN = F / 128;           // waves per node
    constexpr int NPB = 4 / WPN;           // nodes per block
    int wave = threadIdx.x >> 6, lane = threadIdx.x & 63;
    int node = blockIdx.x * NPB + wave / WPN;
    int sub = wave % WPN;
    int f0 = sub * 128 + lane * 2;
    int s = off[node], e = off[node + 1];
    float a0 = 0.f, a1 = 0.f;
    for (int i = s; i < e; i += 8) {
        int id[8];
        #pragma unroll
        for (int j = 0; j < 8; j++) {
            int ii = i + j;
            id[j] = csr[ii < e ? ii : e - 1];
        }
        ushort2 r[8];
        #pragma unroll
        for (int j = 0; j < 8; j++)
            r[j] = *(const ushort2*)(h + (size_t)id[j] * F + f0);
        #pragma unroll
        for (int j = 0; j < 8; j++) {
            if (i + j < e) { a0 += bf2f(r[j].x); a1 += bf2f(r[j].y); }  // wave-uniform pred
        }
    }
    ushort2 o;
    o.x = f2bf(a0); o.y = f2bf(a1);
    *(ushort2*)(outp + (size_t)node * F + f0) = o;
}

// ---------------- layer-3 agg fused with bias+relu+block-partial mean ----------------
// t: bf16 [N,128]. For each node: row = segsum(t) ; v = relu(row + b3).
// Block = 4 nodes; partial[blockIdx][128] = sum of the 4 nodes' v rows.

__global__ __launch_bounds__(256) void agg3_mean_kernel(const unsigned short* __restrict__ t,
                                                        const int* __restrict__ off,
                                                        const int* __restrict__ csr,
                                                        const float* __restrict__ b3,
                                                        float* __restrict__ partial) {
    __shared__ float sm[4 * 128];
    int wave = threadIdx.x >> 6, lane = threadIdx.x & 63;
    int node = blockIdx.x * 4 + wave;
    int f0 = lane * 2;
    int s = off[node], e = off[node + 1];
    float a0 = 0.f, a1 = 0.f;
    for (int i = s; i < e; i += 8) {
        int id[8];
        #pragma unroll
        for (int j = 0; j < 8; j++) {
            int ii = i + j;
            id[j] = csr[ii < e ? ii : e - 1];
        }
        ushort2 r[8];
        #pragma unroll
        for (int j = 0; j < 8; j++)
            r[j] = *(const ushort2*)(t + (size_t)id[j] * 128 + f0);
        #pragma unroll
        for (int j = 0; j < 8; j++) {
            if (i + j < e) { a0 += bf2f(r[j].x); a1 += bf2f(r[j].y); }
        }
    }
    float2 bias = *(const float2*)(b3 + f0);
    sm[wave * 128 + f0]     = fmaxf(a0 + bias.x, 0.f);
    sm[wave * 128 + f0 + 1] = fmaxf(a1 + bias.y, 0.f);
    __syncthreads();
    if (wave == 0) {
        float p0 = sm[f0]     + sm[128 + f0]     + sm[256 + f0]     + sm[384 + f0];
        float p1 = sm[f0 + 1] + sm[128 + f0 + 1] + sm[256 + f0 + 1] + sm[384 + f0 + 1];
        float2 o; o.x = p0; o.y = p1;
        *(float2*)(partial + (size_t)blockIdx.x * 128 + f0) = o;
    }
}

__global__ __launch_bounds__(256) void mean_reduce_kernel(const float* __restrict__ partial,
                                                          float* __restrict__ outp, int nRows) {
    __shared__ float s[256];
    int f = threadIdx.x & 127, half = threadIdx.x >> 7;
    int chunk = (nRows + gridDim.x - 1) / gridDim.x;
    int r0 = blockIdx.x * chunk;
    int r1 = r0 + chunk < nRows ? r0 + chunk : nRows;
    float acc = 0.f;
    for (int r = r0 + half; r < r1; r += 2) acc += partial[(size_t)r * 128 + f];
    s[threadIdx.x] = acc;
    __syncthreads();
    if (half == 0) atomicAdd(&outp[f], (s[f] + s[f + 128]) * (1.0f / N_NODES));
}

// ---------------- bf16 MFMA GEMM ----------------
// C[M,N] = A[M,K] @ B[K,N] (+bias) (relu). A: bf16 MxK. Bt: bf16 NxK (pre-transposed).
// Block 256 thr = 4 waves (2x2), tile 128x128x32, each wave 64x64 via 4x4 mfma 16x16x32.

template<typename T> __device__ inline void storeC(T* p, float v);
template<> __device__ inline void storeC<float>(float* p, float v) { *p = v; }
template<> __device__ inline void storeC<unsigned short>(unsigned short* p, float v) { *p = f2bf(v); }

template<typename OUT_T>
__global__ __launch_bounds__(256) void gemm_bf16_kernel(const unsigned short* __restrict__ A,
                                                        const unsigned short* __restrict__ Bt,
                                                        const float* __restrict__ bias,
                                                        OUT_T* __restrict__ C,
                                                        int M, int K, int N, int doRelu) {
    constexpr int BM = 128, BN = 128, BK = 32, LDA = BK + 8;
    __shared__ unsigned short As[BM * LDA];
    __shared__ unsigned short Bs[BN * LDA];
    int tid = threadIdx.x;
    int m0 = blockIdx.y * BM, n0 = blockIdx.x * BN;
    int wave = tid >> 6, lane = tid & 63;
    int wm = wave >> 1, wn = wave & 1;
    int mlane = lane & 15, kgrp = lane >> 4;

    floatx4 acc[4][4];
    #pragma unroll
    for (int i = 0; i < 4; i++)
        #pragma unroll
        for (int j = 0; j < 4; j++) acc[i][j] = (floatx4){0.f, 0.f, 0.f, 0.f};

    for (int k0 = 0; k0 < K; k0 += BK) {
        #pragma unroll
        for (int it = 0; it < 2; ++it) {
            int c = tid + it * 256;
            int r = c >> 2, cb = (c & 3) * 8;
            int rg = m0 + r;
            short8 v;
            if (rg < M) v = *(const short8*)(A + (size_t)rg * K + k0 + cb);
            else        v = (short8){0, 0, 0, 0, 0, 0, 0, 0};
            *(short8*)&As[r * LDA + cb] = v;
            short8 w = *(const short8*)(Bt + (size_t)(n0 + r) * K + k0 + cb);
            *(short8*)&Bs[r * LDA + cb] = w;
        }
        __syncthreads();
        short8 af[4], bfr[4];
        #pragma unroll
        for (int mt = 0; mt < 4; mt++)
            af[mt] = *(const short8*)&As[(wm * 64 + mt * 16 + mlane) * LDA + kgrp * 8];
        #pragma unroll
        for (int nt = 0; nt < 4; nt++)
            bfr[nt] = *(const short8*)&Bs[(wn * 64 + nt * 16 + mlane) * LDA + kgrp * 8];
        #pragma unroll
        for (int mt = 0; mt < 4; mt++)
            #pragma unroll
            for (int nt = 0; nt < 4; nt++)
                acc[mt][nt] = __builtin_amdgcn_mfma_f32_16x16x32_bf16(af[mt], bfr[nt],
                                                                      acc[mt][nt], 0, 0, 0);
        __syncthreads();
    }
    #pragma unroll
    for (int mt = 0; mt < 4; mt++) {
        #pragma unroll
        for (int nt = 0; nt < 4; nt++) {
            int col = n0 + wn * 64 + nt * 16 + mlane;
            float bv = bias ? bias[col] : 0.f;
            #pragma unroll
            for (int r = 0; r < 4; r++) {
                int row = m0 + wm * 64 + mt * 16 + kgrp * 4 + r;
                if (row < M) {
                    float v = acc[mt][nt][r] + bv;
                    if (doRelu) v = fmaxf(v, 0.f);
                    storeC(C + (size_t)row * N + col, v);
                }
            }
        }
    }
}

// ---------------- launch ----------------

extern "C" void kernel_launch(void* const* d_in, const int* in_sizes, int n_in,
                              void* d_out, int out_size, void* d_ws, size_t ws_size,
                              hipStream_t stream) {
    const float* x   = (const float*)d_in[0];
    const int*   src = (const int*)d_in[1];
    const int*   dst = (const int*)d_in[2];
    const float* W1 = (const float*)d_in[3];
    const float* b1 = (const float*)d_in[4];
    const float* W2 = (const float*)d_in[5];
    const float* b2 = (const float*)d_in[6];
    const float* W3 = (const float*)d_in[7];
    const float* b3 = (const float*)d_in[8];
    float* out = (float*)d_out;

    char* ws = (char*)d_ws;
    size_t o = 0;
    auto alloc = [&](size_t bytes) -> char* {
        char* p = ws + o;
        o = (o + bytes + 255) & ~(size_t)255;
        return p;
    };
    int* off     = (int*)alloc((size_t)(N_NODES + 1) * 4);
    int* cur     = (int*)alloc((size_t)N_NODES * 4);
    int* csr     = (int*)alloc((size_t)N_EDGES * 4);
    int* partial = (int*)alloc((size_t)N_NODES * 4);
    int* bsum    = (int*)alloc(256 * 4);
    unsigned short* Wt1 = (unsigned short*)alloc((size_t)128 * 256 * 2);
    unsigned short* Wt2 = (unsigned short*)alloc((size_t)256 * 256 * 2);
    unsigned short* Wt3 = (unsigned short*)alloc((size_t)256 * 128 * 2);
    char* R1 = alloc((size_t)N_NODES * 256 * 2);  // 25.6 MB
    char* R2 = alloc((size_t)N_NODES * 256 * 2);
    char* R3 = alloc((size_t)N_NODES * 256 * 2);

    unsigned short* xb    = (unsigned short*)R1;  // 50000x128 bf16
    unsigned short* aggX  = (unsigned short*)R2;  // 50000x128 bf16
    unsigned short* h1    = (unsigned short*)R3;  // 50000x256 bf16
    unsigned short* agg2o = (unsigned short*)R1;  // 50000x256 bf16
    unsigned short* h2    = (unsigned short*)R2;  // 50000x256 bf16
    unsigned short* t     = (unsigned short*)R3;  // 50000x128 bf16
    float*          pmean = (float*)R1;           // 12500x128 fp32 partial means

    const int nb = (N_NODES + 255) / 256;  // 196

    // CSR build
    hipMemsetAsync(cur, 0, (size_t)N_NODES * 4, stream);
    hist_kernel<<<(N_EDGES + 255) / 256, 256, 0, stream>>>(dst, cur, N_EDGES);
    scan_block_kernel<<<nb, 256, 0, stream>>>(cur, partial, bsum, N_NODES);
    scan_bsum_kernel<<<1, 256, 0, stream>>>(bsum, nb);
    finalize_kernel<<<nb, 256, 0, stream>>>(partial, bsum, cur, off, N_NODES);
    fill_kernel<<<(N_EDGES + 255) / 256, 256, 0, stream>>>(src, dst, cur, csr, N_EDGES);

    // fused prep: weights -> bf16 [N][K], x -> bf16
    const int prepThreads = 131072 + N_NODES * 128 / 4;
    prep_kernel<<<(prepThreads + 255) / 256, 256, 0, stream>>>(W1, W2, W3, x,
                                                               Wt1, Wt2, Wt3, xb);

    const int mb = (N_NODES + 127) / 128;  // 391

    // Layer 1
    agg_bf_kernel<128><<<N_NODES / 4, 256, 0, stream>>>(xb, off, csr, aggX);
    gemm_bf16_kernel<unsigned short><<<dim3(2, mb), 256, 0, stream>>>(aggX, Wt1, b1, h1,
                                                                      N_NODES, 128, 256, 1);
    // Layer 2
    agg_bf_kernel<256><<<N_NODES / 2, 256, 0, stream>>>(h1, off, csr, agg2o);
    gemm_bf16_kernel<unsigned short><<<dim3(2, mb), 256, 0, stream>>>(agg2o, Wt2, b2, h2,
                                                                      N_NODES, 256, 256, 1);
    // Layer 3 reordered: t = h2 @ W3 (bf16), then fused agg+bias+relu+partial-mean
    gemm_bf16_kernel<unsigned short><<<dim3(1, mb), 256, 0, stream>>>(h2, Wt3, nullptr, t,
                                                                      N_NODES, 256, 128, 0);
    agg3_mean_kernel<<<N_NODES / 4, 256, 0, stream>>>(t, off, csr, b3, pmean);

    hipMemsetAsync(out, 0, 128 * 4, stream);
    mean_reduce_kernel<<<128, 256, 0, stream>>>(pmean, out, N_NODES / 4);
}

// Round 4
// 329.563 us; speedup vs baseline: 2.4842x; 1.0889x over previous
//
#include <hip/hip_runtime.h>

#define N_NODES 50000
#define N_EDGES 500000

typedef __attribute__((ext_vector_type(8))) short short8;
typedef __attribute__((ext_vector_type(4))) float floatx4;

__device__ inline float bf2f(unsigned short u) {
    unsigned int x = ((unsigned int)u) << 16;
    return __builtin_bit_cast(float, x);
}
__device__ inline unsigned short f2bf(float f) {  // round-to-nearest-even
    unsigned int x = __builtin_bit_cast(unsigned int, f);
    x += 0x7fff + ((x >> 16) & 1);
    return (unsigned short)(x >> 16);
}

// ---------------- CSR build ----------------

__global__ void hist_kernel(const int* __restrict__ dst, int* __restrict__ deg, int nE) {
    int e = blockIdx.x * 256 + threadIdx.x;
    if (e < nE) atomicAdd(&deg[dst[e]], 1);
}

__global__ void scan_block_kernel(const int* __restrict__ deg, int* __restrict__ partial,
                                  int* __restrict__ bsum, int n) {
    __shared__ int s[256];
    int i = blockIdx.x * 256 + threadIdx.x;
    int v = (i < n) ? deg[i] : 0;
    s[threadIdx.x] = v;
    __syncthreads();
    #pragma unroll
    for (int d = 1; d < 256; d <<= 1) {
        int t = (threadIdx.x >= d) ? s[threadIdx.x - d] : 0;
        __syncthreads();
        s[threadIdx.x] += t;
        __syncthreads();
    }
    if (i < n) partial[i] = s[threadIdx.x];
    if (threadIdx.x == 255) bsum[blockIdx.x] = s[255];
}

__global__ void scan_bsum_kernel(int* __restrict__ bsum, int nb) {
    __shared__ int s[256];
    int t = threadIdx.x;
    int v = (t < nb) ? bsum[t] : 0;
    s[t] = v;
    __syncthreads();
    #pragma unroll
    for (int d = 1; d < 256; d <<= 1) {
        int u = (t >= d) ? s[t - d] : 0;
        __syncthreads();
        s[t] += u;
        __syncthreads();
    }
    if (t < nb) bsum[t] = s[t];
}

__global__ void finalize_kernel(const int* __restrict__ partial, const int* __restrict__ bsum,
                                int* __restrict__ cur, int* __restrict__ off, int n) {
    int i = blockIdx.x * 256 + threadIdx.x;
    if (i == 0) off[0] = 0;
    if (i < n) {
        int base = (blockIdx.x > 0) ? bsum[blockIdx.x - 1] : 0;
        int incl = base + partial[i];
        off[i + 1] = incl;
        cur[i] = incl - cur[i];
    }
}

__global__ void fill_kernel(const int* __restrict__ src, const int* __restrict__ dst,
                            int* __restrict__ cur, int* __restrict__ csr, int nE) {
    int e = blockIdx.x * 256 + threadIdx.x;
    if (e < nE) {
        int p = atomicAdd(&cur[dst[e]], 1);
        csr[p] = src[e];
    }
}

// ---------------- fused prep: 3 weight transposes (bf16) + x -> bf16 ----------------

__global__ __launch_bounds__(256) void prep_kernel(const float* __restrict__ W1,
                                                   const float* __restrict__ W2,
                                                   const float* __restrict__ W3,
                                                   const float* __restrict__ x,
                                                   unsigned short* __restrict__ Wt1,
                                                   unsigned short* __restrict__ Wt2,
                                                   unsigned short* __restrict__ Wt3,
                                                   unsigned short* __restrict__ xb) {
    int idx = blockIdx.x * 256 + threadIdx.x;
    if (idx < 32768) {
        int k = idx >> 8, n = idx & 255;
        Wt1[n * 128 + k] = f2bf(W1[idx]);
    } else if (idx < 98304) {
        int i = idx - 32768;
        int k = i >> 8, n = i & 255;
        Wt2[n * 256 + k] = f2bf(W2[i]);
    } else if (idx < 131072) {
        int i = idx - 98304;
        int k = i >> 7, n = i & 127;
        Wt3[n * 256 + k] = f2bf(W3[i]);
    } else {
        int i = (idx - 131072) * 4;
        if (i < N_NODES * 128) {
            float4 v = *(const float4*)(x + i);
            ushort4 o;
            o.x = f2bf(v.x); o.y = f2bf(v.y); o.z = f2bf(v.z); o.w = f2bf(v.w);
            *(ushort4*)(xb + i) = o;
        }
    }
}

// ---------------- Aggregation F=256: 1 wave/node, ushort4/lane (full 512B row/load) ----

__global__ __launch_bounds__(256) void agg256_kernel(const unsigned short* __restrict__ h,
                                                     const int* __restrict__ off,
                                                     const int* __restrict__ csr,
                                                     unsigned short* __restrict__ outp) {
    int wave = threadIdx.x >> 6, lane = threadIdx.x & 63;
    int node = blockIdx.x * 4 + wave;
    int f0 = lane * 4;
    int s = __builtin_amdgcn_readfirstlane(off[node]);
    int e = __builtin_amdgcn_readfirstlane(off[node + 1]);
    float a0 = 0.f, a1 = 0.f, a2 = 0.f, a3 = 0.f;
    int i = s;
    for (; i + 8 <= e; i += 8) {           // unconditional main loop
        ushort4 r[8];
        #pragma unroll
        for (int j = 0; j < 8; j++) {
            int id = csr[i + j];            // wave-uniform -> s_load
            r[j] = *(const ushort4*)(h + (size_t)id * 256 + f0);
        }
        #pragma unroll
        for (int j = 0; j < 8; j++) {
            a0 += bf2f(r[j].x); a1 += bf2f(r[j].y);
            a2 += bf2f(r[j].z); a3 += bf2f(r[j].w);
        }
    }
    if (i < e) {                            // single predicated tail block
        ushort4 r[8];
        #pragma unroll
        for (int j = 0; j < 8; j++) {
            int ii = i + j;
            int id = csr[ii < e ? ii : e - 1];   // uniform clamp -> s_load
            r[j] = *(const ushort4*)(h + (size_t)id * 256 + f0);
        }
        #pragma unroll
        for (int j = 0; j < 8; j++) {
            if (i + j < e) {
                a0 += bf2f(r[j].x); a1 += bf2f(r[j].y);
                a2 += bf2f(r[j].z); a3 += bf2f(r[j].w);
            }
        }
    }
    ushort4 o;
    o.x = f2bf(a0); o.y = f2bf(a1); o.z = f2bf(a2); o.w = f2bf(a3);
    *(ushort4*)(outp + (size_t)node * 256 + f0) = o;
}

// ---------------- Aggregation F=128: split-wave (2 edges/load), ushort4/lane ----------
// lanes 0-31: even edges, lanes 32-63: odd edges; combine via shfl_xor(32).

__device__ inline void agg128_body(const unsigned short* __restrict__ h,
                                   const int* __restrict__ off,
                                   const int* __restrict__ csr,
                                   int node, int half, int f0,
                                   float& a0, float& a1, float& a2, float& a3) {
    int s = __builtin_amdgcn_readfirstlane(off[node]);
    int e = __builtin_amdgcn_readfirstlane(off[node + 1]);
    int i = s;
    for (; i + 8 <= e; i += 8) {            // 8 edges = 4 loads, unconditional
        ushort4 r[4];
        #pragma unroll
        for (int j = 0; j < 4; j++) {
            int i0 = csr[i + 2 * j];         // s_load
            int i1 = csr[i + 2 * j + 1];     // s_load
            int id = half ? i1 : i0;         // 1 cndmask
            r[j] = *(const ushort4*)(h + (size_t)id * 128 + f0);
        }
        #pragma unroll
        for (int j = 0; j < 4; j++) {
            a0 += bf2f(r[j].x); a1 += bf2f(r[j].y);
            a2 += bf2f(r[j].z); a3 += bf2f(r[j].w);
        }
    }
    if (i < e) {
        ushort4 r[4];
        #pragma unroll
        for (int j = 0; j < 4; j++) {
            int c0 = i + 2 * j     < e ? i + 2 * j     : e - 1;  // uniform clamps
            int c1 = i + 2 * j + 1 < e ? i + 2 * j + 1 : e - 1;
            int i0 = csr[c0];                // s_load
            int i1 = csr[c1];                // s_load
            int id = half ? i1 : i0;
            r[j] = *(const ushort4*)(h + (size_t)id * 128 + f0);
        }
        #pragma unroll
        for (int j = 0; j < 4; j++) {
            if (i + 2 * j + half < e) {
                a0 += bf2f(r[j].x); a1 += bf2f(r[j].y);
                a2 += bf2f(r[j].z); a3 += bf2f(r[j].w);
            }
        }
    }
    // combine even/odd halves
    a0 += __shfl_xor(a0, 32, 64);
    a1 += __shfl_xor(a1, 32, 64);
    a2 += __shfl_xor(a2, 32, 64);
    a3 += __shfl_xor(a3, 32, 64);
}

__global__ __launch_bounds__(256) void agg128_kernel(const unsigned short* __restrict__ h,
                                                     const int* __restrict__ off,
                                                     const int* __restrict__ csr,
                                                     unsigned short* __restrict__ outp) {
    int wave = threadIdx.x >> 6, lane = threadIdx.x & 63;
    int node = blockIdx.x * 4 + wave;
    int half = lane >> 5;
    int f0 = (lane & 31) * 4;
    float a0, a1, a2, a3;
    a0 = a1 = a2 = a3 = 0.f;
    agg128_body(h, off, csr, node, half, f0, a0, a1, a2, a3);
    if (half == 0) {
        ushort4 o;
        o.x = f2bf(a0); o.y = f2bf(a1); o.z = f2bf(a2); o.w = f2bf(a3);
        *(ushort4*)(outp + (size_t)node * 128 + f0) = o;
    }
}

// ---------------- layer-3: split-wave agg + bias + relu + block partial mean ----------

__global__ __launch_bounds__(256) void agg3_mean_kernel(const unsigned short* __restrict__ t,
                                                        const int* __restrict__ off,
                                                        const int* __restrict__ csr,
                                                        const float* __restrict__ b3,
                                                        float* __restrict__ partial) {
    __shared__ float sm[4 * 128];
    int wave = threadIdx.x >> 6, lane = threadIdx.x & 63;
    int node = blockIdx.x * 4 + wave;
    int half = lane >> 5;
    int f0 = (lane & 31) * 4;
    float a0, a1, a2, a3;
    a0 = a1 = a2 = a3 = 0.f;
    agg128_body(t, off, csr, node, half, f0, a0, a1, a2, a3);
    if (half == 0) {
        float4 bias = *(const float4*)(b3 + f0);
        float4 v;
        v.x = fmaxf(a0 + bias.x, 0.f);
        v.y = fmaxf(a1 + bias.y, 0.f);
        v.z = fmaxf(a2 + bias.z, 0.f);
        v.w = fmaxf(a3 + bias.w, 0.f);
        *(float4*)&sm[wave * 128 + f0] = v;
    }
    __syncthreads();
    if (threadIdx.x < 128) {
        int f = threadIdx.x;
        float p = sm[f] + sm[128 + f] + sm[256 + f] + sm[384 + f];
        partial[(size_t)blockIdx.x * 128 + f] = p;
    }
}

__global__ __launch_bounds__(256) void mean_reduce_kernel(const float* __restrict__ partial,
                                                          float* __restrict__ outp, int nRows) {
    __shared__ float s[256];
    int f = threadIdx.x & 127, half = threadIdx.x >> 7;
    int chunk = (nRows + gridDim.x - 1) / gridDim.x;
    int r0 = blockIdx.x * chunk;
    int r1 = r0 + chunk < nRows ? r0 + chunk : nRows;
    float acc = 0.f;
    for (int r = r0 + half; r < r1; r += 2) acc += partial[(size_t)r * 128 + f];
    s[threadIdx.x] = acc;
    __syncthreads();
    if (half == 0) atomicAdd(&outp[f], (s[f] + s[f + 128]) * (1.0f / N_NODES));
}

// ---------------- bf16 MFMA GEMM ----------------

template<typename T> __device__ inline void storeC(T* p, float v);
template<> __device__ inline void storeC<float>(float* p, float v) { *p = v; }
template<> __device__ inline void storeC<unsigned short>(unsigned short* p, float v) { *p = f2bf(v); }

template<typename OUT_T>
__global__ __launch_bounds__(256) void gemm_bf16_kernel(const unsigned short* __restrict__ A,
                                                        const unsigned short* __restrict__ Bt,
                                                        const float* __restrict__ bias,
                                                        OUT_T* __restrict__ C,
                                                        int M, int K, int N, int doRelu) {
    constexpr int BM = 128, BN = 128, BK = 32, LDA = BK + 8;
    __shared__ unsigned short As[BM * LDA];
    __shared__ unsigned short Bs[BN * LDA];
    int tid = threadIdx.x;
    int m0 = blockIdx.y * BM, n0 = blockIdx.x * BN;
    int wave = tid >> 6, lane = tid & 63;
    int wm = wave >> 1, wn = wave & 1;
    int mlane = lane & 15, kgrp = lane >> 4;

    floatx4 acc[4][4];
    #pragma unroll
    for (int i = 0; i < 4; i++)
        #pragma unroll
        for (int j = 0; j < 4; j++) acc[i][j] = (floatx4){0.f, 0.f, 0.f, 0.f};

    for (int k0 = 0; k0 < K; k0 += BK) {
        #pragma unroll
        for (int it = 0; it < 2; ++it) {
            int c = tid + it * 256;
            int r = c >> 2, cb = (c & 3) * 8;
            int rg = m0 + r;
            short8 v;
            if (rg < M) v = *(const short8*)(A + (size_t)rg * K + k0 + cb);
            else        v = (short8){0, 0, 0, 0, 0, 0, 0, 0};
            *(short8*)&As[r * LDA + cb] = v;
            short8 w = *(const short8*)(Bt + (size_t)(n0 + r) * K + k0 + cb);
            *(short8*)&Bs[r * LDA + cb] = w;
        }
        __syncthreads();
        short8 af[4], bfr[4];
        #pragma unroll
        for (int mt = 0; mt < 4; mt++)
            af[mt] = *(const short8*)&As[(wm * 64 + mt * 16 + mlane) * LDA + kgrp * 8];
        #pragma unroll
        for (int nt = 0; nt < 4; nt++)
            bfr[nt] = *(const short8*)&Bs[(wn * 64 + nt * 16 + mlane) * LDA + kgrp * 8];
        #pragma unroll
        for (int mt = 0; mt < 4; mt++)
            #pragma unroll
            for (int nt = 0; nt < 4; nt++)
                acc[mt][nt] = __builtin_amdgcn_mfma_f32_16x16x32_bf16(af[mt], bfr[nt],
                                                                      acc[mt][nt], 0, 0, 0);
        __syncthreads();
    }
    #pragma unroll
    for (int mt = 0; mt < 4; mt++) {
        #pragma unroll
        for (int nt = 0; nt < 4; nt++) {
            int col = n0 + wn * 64 + nt * 16 + mlane;
            float bv = bias ? bias[col] : 0.f;
            #pragma unroll
            for (int r = 0; r < 4; r++) {
                int row = m0 + wm * 64 + mt * 16 + kgrp * 4 + r;
                if (row < M) {
                    float v = acc[mt][nt][r] + bv;
                    if (doRelu) v = fmaxf(v, 0.f);
                    storeC(C + (size_t)row * N + col, v);
                }
            }
        }
    }
}

// ---------------- launch ----------------

extern "C" void kernel_launch(void* const* d_in, const int* in_sizes, int n_in,
                              void* d_out, int out_size, void* d_ws, size_t ws_size,
                              hipStream_t stream) {
    const float* x   = (const float*)d_in[0];
    const int*   src = (const int*)d_in[1];
    const int*   dst = (const int*)d_in[2];
    const float* W1 = (const float*)d_in[3];
    const float* b1 = (const float*)d_in[4];
    const float* W2 = (const float*)d_in[5];
    const float* b2 = (const float*)d_in[6];
    const float* W3 = (const float*)d_in[7];
    const float* b3 = (const float*)d_in[8];
    float* out = (float*)d_out;

    char* ws = (char*)d_ws;
    size_t o = 0;
    auto alloc = [&](size_t bytes) -> char* {
        char* p = ws + o;
        o = (o + bytes + 255) & ~(size_t)255;
        return p;
    };
    int* off     = (int*)alloc((size_t)(N_NODES + 1) * 4);
    int* cur     = (int*)alloc((size_t)N_NODES * 4);
    int* csr     = (int*)alloc((size_t)N_EDGES * 4);
    int* partial = (int*)alloc((size_t)N_NODES * 4);
    int* bsum    = (int*)alloc(256 * 4);
    unsigned short* Wt1 = (unsigned short*)alloc((size_t)128 * 256 * 2);
    unsigned short* Wt2 = (unsigned short*)alloc((size_t)256 * 256 * 2);
    unsigned short* Wt3 = (unsigned short*)alloc((size_t)256 * 128 * 2);
    char* R1 = alloc((size_t)N_NODES * 256 * 2);
    char* R2 = alloc((size_t)N_NODES * 256 * 2);
    char* R3 = alloc((size_t)N_NODES * 256 * 2);

    unsigned short* xb    = (unsigned short*)R1;  // 50000x128 bf16
    unsigned short* aggX  = (unsigned short*)R2;  // 50000x128 bf16
    unsigned short* h1    = (unsigned short*)R3;  // 50000x256 bf16
    unsigned short* agg2o = (unsigned short*)R1;  // 50000x256 bf16
    unsigned short* h2    = (unsigned short*)R2;  // 50000x256 bf16
    unsigned short* t     = (unsigned short*)R3;  // 50000x128 bf16
    float*          pmean = (float*)R1;           // 12500x128 fp32 partial means

    const int nb = (N_NODES + 255) / 256;  // 196

    // CSR build
    hipMemsetAsync(cur, 0, (size_t)N_NODES * 4, stream);
    hist_kernel<<<(N_EDGES + 255) / 256, 256, 0, stream>>>(dst, cur, N_EDGES);
    scan_block_kernel<<<nb, 256, 0, stream>>>(cur, partial, bsum, N_NODES);
    scan_bsum_kernel<<<1, 256, 0, stream>>>(bsum, nb);
    finalize_kernel<<<nb, 256, 0, stream>>>(partial, bsum, cur, off, N_NODES);
    fill_kernel<<<(N_EDGES + 255) / 256, 256, 0, stream>>>(src, dst, cur, csr, N_EDGES);

    // fused prep
    const int prepThreads = 131072 + N_NODES * 128 / 4;
    prep_kernel<<<(prepThreads + 255) / 256, 256, 0, stream>>>(W1, W2, W3, x,
                                                               Wt1, Wt2, Wt3, xb);

    const int mb = (N_NODES + 127) / 128;  // 391

    // Layer 1
    agg128_kernel<<<N_NODES / 4, 256, 0, stream>>>(xb, off, csr, aggX);
    gemm_bf16_kernel<unsigned short><<<dim3(2, mb), 256, 0, stream>>>(aggX, Wt1, b1, h1,
                                                                      N_NODES, 128, 256, 1);
    // Layer 2
    agg256_kernel<<<N_NODES / 4, 256, 0, stream>>>(h1, off, csr, agg2o);
    gemm_bf16_kernel<unsigned short><<<dim3(2, mb), 256, 0, stream>>>(agg2o, Wt2, b2, h2,
                                                                      N_NODES, 256, 256, 1);
    // Layer 3 reordered: t = h2 @ W3 (bf16), then fused agg+bias+relu+partial-mean
    gemm_bf16_kernel<unsigned short><<<dim3(1, mb), 256, 0, stream>>>(h2, Wt3, nullptr, t,
                                                                      N_NODES, 256, 128, 0);
    agg3_mean_kernel<<<N_NODES / 4, 256, 0, stream>>>(t, off, csr, b3, pmean);

    hipMemsetAsync(out, 0, 128 * 4, stream);
    mean_reduce_kernel<<<128, 256, 0, stream>>>(pmean, out, N_NODES / 4);
}

// Round 5
// 307.421 us; speedup vs baseline: 2.6631x; 1.0720x over previous
//
#include <hip/hip_runtime.h>

#define N_NODES 50000
#define N_EDGES 500000

typedef __attribute__((ext_vector_type(8))) short short8;
typedef __attribute__((ext_vector_type(8))) unsigned short ushort8v;
typedef __attribute__((ext_vector_type(4))) float floatx4;

__device__ inline float bf2f(unsigned short u) {
    unsigned int x = ((unsigned int)u) << 16;
    return __builtin_bit_cast(float, x);
}
__device__ inline unsigned short f2bf(float f) {  // round-to-nearest-even
    unsigned int x = __builtin_bit_cast(unsigned int, f);
    x += 0x7fff + ((x >> 16) & 1);
    return (unsigned short)(x >> 16);
}

// ---------------- CSR build ----------------

__global__ void scan_block_kernel(const int* __restrict__ deg, int* __restrict__ partial,
                                  int* __restrict__ bsum, int n) {
    __shared__ int s[256];
    int i = blockIdx.x * 256 + threadIdx.x;
    int v = (i < n) ? deg[i] : 0;
    s[threadIdx.x] = v;
    __syncthreads();
    #pragma unroll
    for (int d = 1; d < 256; d <<= 1) {
        int t = (threadIdx.x >= d) ? s[threadIdx.x - d] : 0;
        __syncthreads();
        s[threadIdx.x] += t;
        __syncthreads();
    }
    if (i < n) partial[i] = s[threadIdx.x];
    if (threadIdx.x == 255) bsum[blockIdx.x] = s[255];
}

__global__ void scan_bsum_kernel(int* __restrict__ bsum, int nb) {
    __shared__ int s[256];
    int t = threadIdx.x;
    int v = (t < nb) ? bsum[t] : 0;
    s[t] = v;
    __syncthreads();
    #pragma unroll
    for (int d = 1; d < 256; d <<= 1) {
        int u = (t >= d) ? s[t - d] : 0;
        __syncthreads();
        s[t] += u;
        __syncthreads();
    }
    if (t < nb) bsum[t] = s[t];
}

__global__ void finalize_kernel(const int* __restrict__ partial, const int* __restrict__ bsum,
                                int* __restrict__ cur, int* __restrict__ off, int n) {
    int i = blockIdx.x * 256 + threadIdx.x;
    if (i == 0) off[0] = 0;
    if (i < n) {
        int base = (blockIdx.x > 0) ? bsum[blockIdx.x - 1] : 0;
        int incl = base + partial[i];
        off[i + 1] = incl;
        cur[i] = incl - cur[i];
    }
}

__global__ void fill_kernel(const int* __restrict__ src, const int* __restrict__ dst,
                            int* __restrict__ cur, int* __restrict__ csr, int nE) {
    int e = blockIdx.x * 256 + threadIdx.x;
    if (e < nE) {
        int p = atomicAdd(&cur[dst[e]], 1);
        csr[p] = src[e];
    }
}

// ---------------- merged hist + prep (weight transpose + x->bf16) ----------------
// region [0, N_EDGES): degree histogram
// then 32768 (Wt1), 65536 (Wt2), 32768 (Wt3), then x float4->bf16x4

__global__ __launch_bounds__(256) void histprep_kernel(const int* __restrict__ dst,
                                                       int* __restrict__ deg,
                                                       const float* __restrict__ W1,
                                                       const float* __restrict__ W2,
                                                       const float* __restrict__ W3,
                                                       const float* __restrict__ x,
                                                       unsigned short* __restrict__ Wt1,
                                                       unsigned short* __restrict__ Wt2,
                                                       unsigned short* __restrict__ Wt3,
                                                       unsigned short* __restrict__ xb) {
    int idx = blockIdx.x * 256 + threadIdx.x;
    if (idx < N_EDGES) { atomicAdd(&deg[dst[idx]], 1); return; }
    idx -= N_EDGES;
    if (idx < 32768) {
        int k = idx >> 8, n = idx & 255;
        Wt1[n * 128 + k] = f2bf(W1[idx]);
    } else if (idx < 98304) {
        int i = idx - 32768;
        int k = i >> 8, n = i & 255;
        Wt2[n * 256 + k] = f2bf(W2[i]);
    } else if (idx < 131072) {
        int i = idx - 98304;
        int k = i >> 7, n = i & 127;
        Wt3[n * 256 + k] = f2bf(W3[i]);
    } else {
        int i = (idx - 131072) * 4;
        if (i < N_NODES * 128) {
            float4 v = *(const float4*)(x + i);
            ushort4 o;
            o.x = f2bf(v.x); o.y = f2bf(v.y); o.z = f2bf(v.z); o.w = f2bf(v.w);
            *(ushort4*)(xb + i) = o;
        }
    }
}

// ---------------- Aggregation F=256: half-split wave, ushort8 (16B)/lane -----------
// lanes 0-31: even edge, lanes 32-63: odd edge; 2 edges per VMEM round.

__global__ __launch_bounds__(256) void agg256_kernel(const unsigned short* __restrict__ h,
                                                     const int* __restrict__ off,
                                                     const int* __restrict__ csr,
                                                     unsigned short* __restrict__ outp) {
    int wave = threadIdx.x >> 6, lane = threadIdx.x & 63;
    int node = blockIdx.x * 4 + wave;
    int half = lane >> 5;
    int f0 = (lane & 31) * 8;                 // 32 lanes x 8 = 256 feats
    int s = __builtin_amdgcn_readfirstlane(off[node]);
    int e = __builtin_amdgcn_readfirstlane(off[node + 1]);
    float a[8];
    #pragma unroll
    for (int k = 0; k < 8; k++) a[k] = 0.f;
    int i = s;
    for (; i + 8 <= e; i += 8) {              // 8 edges = 4 rounds
        ushort8v r[4];
        #pragma unroll
        for (int j = 0; j < 4; j++) {
            int i0 = csr[i + 2 * j];           // s_load
            int i1 = csr[i + 2 * j + 1];       // s_load
            int id = half ? i1 : i0;
            r[j] = *(const ushort8v*)(h + (size_t)id * 256 + f0);
        }
        #pragma unroll
        for (int j = 0; j < 4; j++)
            #pragma unroll
            for (int k = 0; k < 8; k++) a[k] += bf2f(r[j][k]);
    }
    if (i < e) {                               // single predicated tail
        ushort8v r[4];
        #pragma unroll
        for (int j = 0; j < 4; j++) {
            int b0 = i + 2 * j, b1 = i + 2 * j + 1;
            int i0 = csr[b0 < e ? b0 : e - 1];
            int i1 = csr[b1 < e ? b1 : e - 1];
            int id = half ? i1 : i0;
            r[j] = *(const ushort8v*)(h + (size_t)id * 256 + f0);
        }
        #pragma unroll
        for (int j = 0; j < 4; j++) {
            if (i + 2 * j + half < e) {
                #pragma unroll
                for (int k = 0; k < 8; k++) a[k] += bf2f(r[j][k]);
            }
        }
    }
    #pragma unroll
    for (int k = 0; k < 8; k++) a[k] += __shfl_xor(a[k], 32, 64);
    if (half == 0) {
        ushort8v o;
        #pragma unroll
        for (int k = 0; k < 8; k++) o[k] = f2bf(a[k]);
        *(ushort8v*)(outp + (size_t)node * 256 + f0) = o;
    }
}

// ---------------- Aggregation F=128: quad-split wave, ushort8/lane ------------------
// 16 lanes per edge, 4 edges per VMEM round; combine via shfl_xor(16), shfl_xor(32).

__device__ inline void agg128_body(const unsigned short* __restrict__ h,
                                   const int* __restrict__ off,
                                   const int* __restrict__ csr,
                                   int node, int quad, int f0, float* a) {
    int s = __builtin_amdgcn_readfirstlane(off[node]);
    int e = __builtin_amdgcn_readfirstlane(off[node + 1]);
    int i = s;
    for (; i + 8 <= e; i += 8) {              // 8 edges = 2 rounds
        ushort8v r[2];
        #pragma unroll
        for (int j = 0; j < 2; j++) {
            int base = i + 4 * j;
            int i0 = csr[base], i1 = csr[base + 1], i2 = csr[base + 2], i3 = csr[base + 3];
            int id = quad == 0 ? i0 : quad == 1 ? i1 : quad == 2 ? i2 : i3;
            r[j] = *(const ushort8v*)(h + (size_t)id * 128 + f0);
        }
        #pragma unroll
        for (int j = 0; j < 2; j++)
            #pragma unroll
            for (int k = 0; k < 8; k++) a[k] += bf2f(r[j][k]);
    }
    if (i < e) {
        ushort8v r[2];
        #pragma unroll
        for (int j = 0; j < 2; j++) {
            int base = i + 4 * j;
            int c0 = base < e ? base : e - 1;
            int c1 = base + 1 < e ? base + 1 : e - 1;
            int c2 = base + 2 < e ? base + 2 : e - 1;
            int c3 = base + 3 < e ? base + 3 : e - 1;
            int i0 = csr[c0], i1 = csr[c1], i2 = csr[c2], i3 = csr[c3];
            int id = quad == 0 ? i0 : quad == 1 ? i1 : quad == 2 ? i2 : i3;
            r[j] = *(const ushort8v*)(h + (size_t)id * 128 + f0);
        }
        #pragma unroll
        for (int j = 0; j < 2; j++) {
            if (i + 4 * j + quad < e) {
                #pragma unroll
                for (int k = 0; k < 8; k++) a[k] += bf2f(r[j][k]);
            }
        }
    }
    #pragma unroll
    for (int k = 0; k < 8; k++) {
        a[k] += __shfl_xor(a[k], 16, 64);
        a[k] += __shfl_xor(a[k], 32, 64);
    }
}

__global__ __launch_bounds__(256) void agg128_kernel(const unsigned short* __restrict__ h,
                                                     const int* __restrict__ off,
                                                     const int* __restrict__ csr,
                                                     unsigned short* __restrict__ outp) {
    int wave = threadIdx.x >> 6, lane = threadIdx.x & 63;
    int node = blockIdx.x * 4 + wave;
    int quad = lane >> 4;
    int f0 = (lane & 15) * 8;                 // 16 lanes x 8 = 128 feats
    float a[8];
    #pragma unroll
    for (int k = 0; k < 8; k++) a[k] = 0.f;
    agg128_body(h, off, csr, node, quad, f0, a);
    if (quad == 0) {
        ushort8v o;
        #pragma unroll
        for (int k = 0; k < 8; k++) o[k] = f2bf(a[k]);
        *(ushort8v*)(outp + (size_t)node * 128 + f0) = o;
    }
}

// ---------------- layer-3: quad-split agg + bias + relu + block partial mean -------

__global__ __launch_bounds__(256) void agg3_mean_kernel(const unsigned short* __restrict__ t,
                                                        const int* __restrict__ off,
                                                        const int* __restrict__ csr,
                                                        const float* __restrict__ b3,
                                                        float* __restrict__ partial) {
    __shared__ float sm[4 * 128];
    int wave = threadIdx.x >> 6, lane = threadIdx.x & 63;
    int node = blockIdx.x * 4 + wave;
    int quad = lane >> 4;
    int f0 = (lane & 15) * 8;
    float a[8];
    #pragma unroll
    for (int k = 0; k < 8; k++) a[k] = 0.f;
    agg128_body(t, off, csr, node, quad, f0, a);
    if (quad == 0) {
        #pragma unroll
        for (int k = 0; k < 8; k++)
            sm[wave * 128 + f0 + k] = fmaxf(a[k] + b3[f0 + k], 0.f);
    }
    __syncthreads();
    if (threadIdx.x < 128) {
        int f = threadIdx.x;
        float p = sm[f] + sm[128 + f] + sm[256 + f] + sm[384 + f];
        partial[(size_t)blockIdx.x * 128 + f] = p;
    }
}

__global__ __launch_bounds__(256) void mean_reduce_kernel(const float* __restrict__ partial,
                                                          float* __restrict__ outp, int nRows) {
    __shared__ float s[256];
    int f = threadIdx.x & 127, half = threadIdx.x >> 7;
    int chunk = (nRows + gridDim.x - 1) / gridDim.x;
    int r0 = blockIdx.x * chunk;
    int r1 = r0 + chunk < nRows ? r0 + chunk : nRows;
    float acc = 0.f;
    for (int r = r0 + half; r < r1; r += 2) acc += partial[(size_t)r * 128 + f];
    s[threadIdx.x] = acc;
    __syncthreads();
    if (half == 0) atomicAdd(&outp[f], (s[f] + s[f + 128]) * (1.0f / N_NODES));
}

// ---------------- bf16 MFMA GEMM, tile 128xBN (BN=128: 4 waves, BN=256: 8 waves) ----
// A fetched once per row-strip when grid.x == 1 (N == BN).

template<typename T> __device__ inline void storeC(T* p, float v);
template<> __device__ inline void storeC<float>(float* p, float v) { *p = v; }
template<> __device__ inline void storeC<unsigned short>(unsigned short* p, float v) { *p = f2bf(v); }

template<int BN, typename OUT_T>
__global__ __launch_bounds__(2 * BN) void gemm_bf16_kernel(const unsigned short* __restrict__ A,
                                                           const unsigned short* __restrict__ Bt,
                                                           const float* __restrict__ bias,
                                                           OUT_T* __restrict__ C,
                                                           int M, int K, int N, int doRelu) {
    constexpr int BM = 128, BK = 32, LDA = BK + 8;
    constexpr int T = 2 * BN;                 // threads
    __shared__ unsigned short As[BM * LDA];
    __shared__ unsigned short Bs[BN * LDA];
    int tid = threadIdx.x;
    int m0 = blockIdx.y * BM, n0 = blockIdx.x * BN;
    int wave = tid >> 6, lane = tid & 63;
    int wm = wave & 1, wn = wave >> 1;        // wn in [0, BN/64)
    int mlane = lane & 15, kgrp = lane >> 4;

    floatx4 acc[4][4];
    #pragma unroll
    for (int i = 0; i < 4; i++)
        #pragma unroll
        for (int j = 0; j < 4; j++) acc[i][j] = (floatx4){0.f, 0.f, 0.f, 0.f};

    for (int k0 = 0; k0 < K; k0 += BK) {
        #pragma unroll
        for (int c = tid; c < 512; c += T) {          // A: 128x32 = 512 chunks of 8
            int r = c >> 2, cb = (c & 3) * 8;
            int rg = m0 + r;
            short8 v;
            if (rg < M) v = *(const short8*)(A + (size_t)rg * K + k0 + cb);
            else        v = (short8){0, 0, 0, 0, 0, 0, 0, 0};
            *(short8*)&As[r * LDA + cb] = v;
        }
        #pragma unroll
        for (int c = tid; c < BN * 4; c += T) {       // B: BNx32 chunks of 8
            int r = c >> 2, cb = (c & 3) * 8;
            short8 w = *(const short8*)(Bt + (size_t)(n0 + r) * K + k0 + cb);
            *(short8*)&Bs[r * LDA + cb] = w;
        }
        __syncthreads();
        short8 af[4], bfr[4];
        #pragma unroll
        for (int mt = 0; mt < 4; mt++)
            af[mt] = *(const short8*)&As[(wm * 64 + mt * 16 + mlane) * LDA + kgrp * 8];
        #pragma unroll
        for (int nt = 0; nt < 4; nt++)
            bfr[nt] = *(const short8*)&Bs[(wn * 64 + nt * 16 + mlane) * LDA + kgrp * 8];
        #pragma unroll
        for (int mt = 0; mt < 4; mt++)
            #pragma unroll
            for (int nt = 0; nt < 4; nt++)
                acc[mt][nt] = __builtin_amdgcn_mfma_f32_16x16x32_bf16(af[mt], bfr[nt],
                                                                      acc[mt][nt], 0, 0, 0);
        __syncthreads();
    }
    #pragma unroll
    for (int mt = 0; mt < 4; mt++) {
        #pragma unroll
        for (int nt = 0; nt < 4; nt++) {
            int col = n0 + wn * 64 + nt * 16 + mlane;
            float bv = bias ? bias[col] : 0.f;
            #pragma unroll
            for (int r = 0; r < 4; r++) {
                int row = m0 + wm * 64 + mt * 16 + kgrp * 4 + r;
                if (row < M) {
                    float v = acc[mt][nt][r] + bv;
                    if (doRelu) v = fmaxf(v, 0.f);
                    storeC(C + (size_t)row * N + col, v);
                }
            }
        }
    }
}

// ---------------- launch ----------------

extern "C" void kernel_launch(void* const* d_in, const int* in_sizes, int n_in,
                              void* d_out, int out_size, void* d_ws, size_t ws_size,
                              hipStream_t stream) {
    const float* x   = (const float*)d_in[0];
    const int*   src = (const int*)d_in[1];
    const int*   dst = (const int*)d_in[2];
    const float* W1 = (const float*)d_in[3];
    const float* b1 = (const float*)d_in[4];
    const float* W2 = (const float*)d_in[5];
    const float* b2 = (const float*)d_in[6];
    const float* W3 = (const float*)d_in[7];
    const float* b3 = (const float*)d_in[8];
    float* out = (float*)d_out;

    char* ws = (char*)d_ws;
    size_t o = 0;
    auto alloc = [&](size_t bytes) -> char* {
        char* p = ws + o;
        o = (o + bytes + 255) & ~(size_t)255;
        return p;
    };
    int* off     = (int*)alloc((size_t)(N_NODES + 1) * 4);
    int* cur     = (int*)alloc((size_t)N_NODES * 4);
    int* csr     = (int*)alloc((size_t)N_EDGES * 4);
    int* partial = (int*)alloc((size_t)N_NODES * 4);
    int* bsum    = (int*)alloc(256 * 4);
    unsigned short* Wt1 = (unsigned short*)alloc((size_t)128 * 256 * 2);
    unsigned short* Wt2 = (unsigned short*)alloc((size_t)256 * 256 * 2);
    unsigned short* Wt3 = (unsigned short*)alloc((size_t)256 * 128 * 2);
    char* R1 = alloc((size_t)N_NODES * 256 * 2);
    char* R2 = alloc((size_t)N_NODES * 256 * 2);
    char* R3 = alloc((size_t)N_NODES * 256 * 2);

    unsigned short* xb    = (unsigned short*)R1;  // 50000x128 bf16
    unsigned short* aggX  = (unsigned short*)R2;  // 50000x128 bf16
    unsigned short* h1    = (unsigned short*)R3;  // 50000x256 bf16
    unsigned short* agg2o = (unsigned short*)R1;  // 50000x256 bf16
    unsigned short* h2    = (unsigned short*)R2;  // 50000x256 bf16
    unsigned short* t     = (unsigned short*)R3;  // 50000x128 bf16
    float*          pmean = (float*)R1;           // 12500x128 fp32 partial means

    const int nb = (N_NODES + 255) / 256;  // 196

    hipMemsetAsync(cur, 0, (size_t)N_NODES * 4, stream);
    // merged histogram + weight transpose + x->bf16
    const int hpThreads = N_EDGES + 131072 + N_NODES * 128 / 4;
    histprep_kernel<<<(hpThreads + 255) / 256, 256, 0, stream>>>(dst, cur, W1, W2, W3, x,
                                                                 Wt1, Wt2, Wt3, xb);
    scan_block_kernel<<<nb, 256, 0, stream>>>(cur, partial, bsum, N_NODES);
    scan_bsum_kernel<<<1, 256, 0, stream>>>(bsum, nb);
    finalize_kernel<<<nb, 256, 0, stream>>>(partial, bsum, cur, off, N_NODES);
    fill_kernel<<<(N_EDGES + 255) / 256, 256, 0, stream>>>(src, dst, cur, csr, N_EDGES);

    const int mb = (N_NODES + 127) / 128;  // 391

    // Layer 1
    agg128_kernel<<<N_NODES / 4, 256, 0, stream>>>(xb, off, csr, aggX);
    gemm_bf16_kernel<256, unsigned short><<<dim3(1, mb), 512, 0, stream>>>(aggX, Wt1, b1, h1,
                                                                           N_NODES, 128, 256, 1);
    // Layer 2
    agg256_kernel<<<N_NODES / 4, 256, 0, stream>>>(h1, off, csr, agg2o);
    gemm_bf16_kernel<256, unsigned short><<<dim3(1, mb), 512, 0, stream>>>(agg2o, Wt2, b2, h2,
                                                                           N_NODES, 256, 256, 1);
    // Layer 3 reordered: t = h2 @ W3 (bf16), then fused agg+bias+relu+partial-mean
    gemm_bf16_kernel<128, unsigned short><<<dim3(1, mb), 256, 0, stream>>>(h2, Wt3, nullptr, t,
                                                                           N_NODES, 256, 128, 0);
    agg3_mean_kernel<<<N_NODES / 4, 256, 0, stream>>>(t, off, csr, b3, pmean);

    hipMemsetAsync(out, 0, 128 * 4, stream);
    mean_reduce_kernel<<<128, 256, 0, stream>>>(pmean, out, N_NODES / 4);
}

// Round 6
// 301.256 us; speedup vs baseline: 2.7176x; 1.0205x over previous
//
#include <hip/hip_runtime.h>

#define N_NODES 50000
#define N_EDGES 500000

typedef __attribute__((ext_vector_type(8))) short short8;
typedef __attribute__((ext_vector_type(8))) unsigned short ushort8v;
typedef __attribute__((ext_vector_type(4))) float floatx4;
typedef __attribute__((ext_vector_type(4))) unsigned int uint4v;

__device__ inline float bf2f(unsigned short u) {
    unsigned int x = ((unsigned int)u) << 16;
    return __builtin_bit_cast(float, x);
}
__device__ inline unsigned short f2bf(float f) {  // round-to-nearest-even
    unsigned int x = __builtin_bit_cast(unsigned int, f);
    x += 0x7fff + ((x >> 16) & 1);
    return (unsigned short)(x >> 16);
}

// accumulate 8 bf16 (16B) into 4 float2 pairs: lo = u<<16, hi = u & 0xFFFF0000
__device__ inline void accum16B(float2* a, ushort8v rv) {
    uint4v u = __builtin_bit_cast(uint4v, rv);
    #pragma unroll
    for (int p = 0; p < 4; p++) {
        float lo = __builtin_bit_cast(float, u[p] << 16);
        float hi = __builtin_bit_cast(float, u[p] & 0xFFFF0000u);
        a[p].x += lo;
        a[p].y += hi;
    }
}

// ---------------- CSR build ----------------

__global__ void scan_block_kernel(const int* __restrict__ deg, int* __restrict__ partial,
                                  int* __restrict__ bsum, int n) {
    __shared__ int s[256];
    int i = blockIdx.x * 256 + threadIdx.x;
    int v = (i < n) ? deg[i] : 0;
    s[threadIdx.x] = v;
    __syncthreads();
    #pragma unroll
    for (int d = 1; d < 256; d <<= 1) {
        int t = (threadIdx.x >= d) ? s[threadIdx.x - d] : 0;
        __syncthreads();
        s[threadIdx.x] += t;
        __syncthreads();
    }
    if (i < n) partial[i] = s[threadIdx.x];
    if (threadIdx.x == 255) bsum[blockIdx.x] = s[255];
}

// merged: per-block prefix over raw bsum + finalize (kills scan_bsum launch)
__global__ __launch_bounds__(256) void finalize_kernel(const int* __restrict__ partial,
                                                       const int* __restrict__ bsum,
                                                       int* __restrict__ cur,
                                                       int* __restrict__ off, int n) {
    __shared__ int sr[256];
    int t = threadIdx.x;
    sr[t] = (t < blockIdx.x) ? bsum[t] : 0;   // raw block totals of preceding blocks
    __syncthreads();
    #pragma unroll
    for (int d = 128; d > 0; d >>= 1) {
        if (t < d) sr[t] += sr[t + d];
        __syncthreads();
    }
    int base = sr[0];
    int i = blockIdx.x * 256 + t;
    if (i == 0) off[0] = 0;
    if (i < n) {
        int incl = base + partial[i];
        off[i + 1] = incl;
        cur[i] = incl - cur[i];   // cur held deg; now row start
    }
}

__global__ void fill_kernel(const int* __restrict__ src, const int* __restrict__ dst,
                            int* __restrict__ cur, int* __restrict__ csr, int nE) {
    int e = blockIdx.x * 256 + threadIdx.x;
    if (e < nE) {
        int p = atomicAdd(&cur[dst[e]], 1);
        csr[p] = src[e];
    }
}

// ---------------- merged hist + prep (weight transpose + x->bf16) ----------------

__global__ __launch_bounds__(256) void histprep_kernel(const int* __restrict__ dst,
                                                       int* __restrict__ deg,
                                                       const float* __restrict__ W1,
                                                       const float* __restrict__ W2,
                                                       const float* __restrict__ W3,
                                                       const float* __restrict__ x,
                                                       unsigned short* __restrict__ Wt1,
                                                       unsigned short* __restrict__ Wt2,
                                                       unsigned short* __restrict__ Wt3,
                                                       unsigned short* __restrict__ xb) {
    int idx = blockIdx.x * 256 + threadIdx.x;
    if (idx < N_EDGES) { atomicAdd(&deg[dst[idx]], 1); return; }
    idx -= N_EDGES;
    if (idx < 32768) {
        int k = idx >> 8, n = idx & 255;
        Wt1[n * 128 + k] = f2bf(W1[idx]);
    } else if (idx < 98304) {
        int i = idx - 32768;
        int k = i >> 8, n = i & 255;
        Wt2[n * 256 + k] = f2bf(W2[i]);
    } else if (idx < 131072) {
        int i = idx - 98304;
        int k = i >> 7, n = i & 127;
        Wt3[n * 256 + k] = f2bf(W3[i]);
    } else {
        int i = (idx - 131072) * 4;
        if (i < N_NODES * 128) {
            float4 v = *(const float4*)(x + i);
            ushort4 o;
            o.x = f2bf(v.x); o.y = f2bf(v.y); o.z = f2bf(v.z); o.w = f2bf(v.w);
            *(ushort4*)(xb + i) = o;
        }
    }
}

// ---------------- Aggregation F=256: half-split wave, 16B/lane, exact-round tail ----

__global__ __launch_bounds__(256) void agg256_kernel(const unsigned short* __restrict__ h,
                                                     const int* __restrict__ off,
                                                     const int* __restrict__ csr,
                                                     unsigned short* __restrict__ outp) {
    int wave = threadIdx.x >> 6, lane = threadIdx.x & 63;
    int node = blockIdx.x * 4 + wave;
    int half = lane >> 5;
    int f0 = (lane & 31) * 8;
    int s = __builtin_amdgcn_readfirstlane(off[node]);
    int e = __builtin_amdgcn_readfirstlane(off[node + 1]);
    float2 a[4];
    #pragma unroll
    for (int p = 0; p < 4; p++) a[p] = make_float2(0.f, 0.f);
    int i = s;
    for (; i + 8 <= e; i += 8) {              // 8 edges = 4 rounds, unconditional
        ushort8v r[4];
        #pragma unroll
        for (int j = 0; j < 4; j++) {
            int i0 = csr[i + 2 * j];           // s_load (wave-uniform)
            int i1 = csr[i + 2 * j + 1];
            int id = half ? i1 : i0;
            r[j] = *(const ushort8v*)(h + (size_t)id * 256 + f0);
        }
        #pragma unroll
        for (int j = 0; j < 4; j++) accum16B(a, r[j]);
    }
    int rem = e - i;                           // 0..7
    if (rem > 0) {
        int nr = (rem + 1) >> 1;               // rounds actually needed (1..4)
        ushort8v r[4];
        #pragma unroll
        for (int j = 0; j < 4; j++) {
            if (j < nr) {                      // uniform scalar branch
                int b0 = i + 2 * j, b1 = b0 + 1;
                int i0 = csr[b0];              // b0 < e guaranteed by j < nr
                int i1 = csr[b1 < e ? b1 : e - 1];
                int id = half ? i1 : i0;
                r[j] = *(const ushort8v*)(h + (size_t)id * 256 + f0);
            }
        }
        #pragma unroll
        for (int j = 0; j < 4; j++) {
            if (j < nr && (i + 2 * j + half) < e) accum16B(a, r[j]);
        }
    }
    #pragma unroll
    for (int p = 0; p < 4; p++) {
        a[p].x += __shfl_xor(a[p].x, 32, 64);
        a[p].y += __shfl_xor(a[p].y, 32, 64);
    }
    if (half == 0) {
        ushort8v o;
        #pragma unroll
        for (int p = 0; p < 4; p++) { o[2 * p] = f2bf(a[p].x); o[2 * p + 1] = f2bf(a[p].y); }
        *(ushort8v*)(outp + (size_t)node * 256 + f0) = o;
    }
}

// ---------------- Aggregation F=128: quad-split wave, 16B/lane, exact-round tail ----
// 16 lanes/edge, 4 edges/round; combine via shfl_xor(16), shfl_xor(32).

__device__ inline void agg128_body(const unsigned short* __restrict__ h,
                                   const int* __restrict__ off,
                                   const int* __restrict__ csr,
                                   int node, int quad, int f0, float2* a) {
    int s = __builtin_amdgcn_readfirstlane(off[node]);
    int e = __builtin_amdgcn_readfirstlane(off[node + 1]);
    int i = s;
    for (; i + 8 <= e; i += 8) {              // 8 edges = 2 rounds
        ushort8v r[2];
        #pragma unroll
        for (int j = 0; j < 2; j++) {
            int base = i + 4 * j;
            int i0 = csr[base], i1 = csr[base + 1], i2 = csr[base + 2], i3 = csr[base + 3];
            int id = quad == 0 ? i0 : quad == 1 ? i1 : quad == 2 ? i2 : i3;
            r[j] = *(const ushort8v*)(h + (size_t)id * 128 + f0);
        }
        #pragma unroll
        for (int j = 0; j < 2; j++) accum16B(a, r[j]);
    }
    int rem = e - i;                           // 0..7
    if (rem > 0) {
        int nr = (rem + 3) >> 2;               // 1 or 2 rounds
        ushort8v r[2];
        #pragma unroll
        for (int j = 0; j < 2; j++) {
            if (j < nr) {                      // uniform scalar branch
                int base = i + 4 * j;
                int c0 = base;                 // base < e guaranteed by j < nr
                int c1 = base + 1 < e ? base + 1 : e - 1;
                int c2 = base + 2 < e ? base + 2 : e - 1;
                int c3 = base + 3 < e ? base + 3 : e - 1;
                int i0 = csr[c0], i1 = csr[c1], i2 = csr[c2], i3 = csr[c3];
                int id = quad == 0 ? i0 : quad == 1 ? i1 : quad == 2 ? i2 : i3;
                r[j] = *(const ushort8v*)(h + (size_t)id * 128 + f0);
            }
        }
        #pragma unroll
        for (int j = 0; j < 2; j++) {
            if (j < nr && (i + 4 * j + quad) < e) accum16B(a, r[j]);
        }
    }
    #pragma unroll
    for (int p = 0; p < 4; p++) {
        a[p].x += __shfl_xor(a[p].x, 16, 64);
        a[p].y += __shfl_xor(a[p].y, 16, 64);
        a[p].x += __shfl_xor(a[p].x, 32, 64);
        a[p].y += __shfl_xor(a[p].y, 32, 64);
    }
}

__global__ __launch_bounds__(256) void agg128_kernel(const unsigned short* __restrict__ h,
                                                     const int* __restrict__ off,
                                                     const int* __restrict__ csr,
                                                     unsigned short* __restrict__ outp) {
    int wave = threadIdx.x >> 6, lane = threadIdx.x & 63;
    int node = blockIdx.x * 4 + wave;
    int quad = lane >> 4;
    int f0 = (lane & 15) * 8;
    float2 a[4];
    #pragma unroll
    for (int p = 0; p < 4; p++) a[p] = make_float2(0.f, 0.f);
    agg128_body(h, off, csr, node, quad, f0, a);
    if (quad == 0) {
        ushort8v o;
        #pragma unroll
        for (int p = 0; p < 4; p++) { o[2 * p] = f2bf(a[p].x); o[2 * p + 1] = f2bf(a[p].y); }
        *(ushort8v*)(outp + (size_t)node * 128 + f0) = o;
    }
}

// ---------------- layer-3: quad-split agg + bias + relu + block partial mean -------

__global__ __launch_bounds__(256) void agg3_mean_kernel(const unsigned short* __restrict__ t,
                                                        const int* __restrict__ off,
                                                        const int* __restrict__ csr,
                                                        const float* __restrict__ b3,
                                                        float* __restrict__ partial) {
    __shared__ float sm[4 * 128];
    int wave = threadIdx.x >> 6, lane = threadIdx.x & 63;
    int node = blockIdx.x * 4 + wave;
    int quad = lane >> 4;
    int f0 = (lane & 15) * 8;
    float2 a[4];
    #pragma unroll
    for (int p = 0; p < 4; p++) a[p] = make_float2(0.f, 0.f);
    agg128_body(t, off, csr, node, quad, f0, a);
    if (quad == 0) {
        #pragma unroll
        for (int p = 0; p < 4; p++) {
            sm[wave * 128 + f0 + 2 * p]     = fmaxf(a[p].x + b3[f0 + 2 * p], 0.f);
            sm[wave * 128 + f0 + 2 * p + 1] = fmaxf(a[p].y + b3[f0 + 2 * p + 1], 0.f);
        }
    }
    __syncthreads();
    if (threadIdx.x < 128) {
        int f = threadIdx.x;
        float p = sm[f] + sm[128 + f] + sm[256 + f] + sm[384 + f];
        partial[(size_t)blockIdx.x * 128 + f] = p;
    }
}

__global__ __launch_bounds__(256) void mean_reduce_kernel(const float* __restrict__ partial,
                                                          float* __restrict__ outp, int nRows) {
    __shared__ float s[256];
    int f = threadIdx.x & 127, half = threadIdx.x >> 7;
    int chunk = (nRows + gridDim.x - 1) / gridDim.x;
    int r0 = blockIdx.x * chunk;
    int r1 = r0 + chunk < nRows ? r0 + chunk : nRows;
    float acc = 0.f;
    for (int r = r0 + half; r < r1; r += 2) acc += partial[(size_t)r * 128 + f];
    s[threadIdx.x] = acc;
    __syncthreads();
    if (half == 0) atomicAdd(&outp[f], (s[f] + s[f + 128]) * (1.0f / N_NODES));
}

// ---------------- bf16 MFMA GEMM, tile 128xBN (BN=128: 4 waves, BN=256: 8 waves) ----

template<typename T> __device__ inline void storeC(T* p, float v);
template<> __device__ inline void storeC<float>(float* p, float v) { *p = v; }
template<> __device__ inline void storeC<unsigned short>(unsigned short* p, float v) { *p = f2bf(v); }

template<int BN, typename OUT_T>
__global__ __launch_bounds__(2 * BN) void gemm_bf16_kernel(const unsigned short* __restrict__ A,
                                                           const unsigned short* __restrict__ Bt,
                                                           const float* __restrict__ bias,
                                                           OUT_T* __restrict__ C,
                                                           int M, int K, int N, int doRelu) {
    constexpr int BM = 128, BK = 32, LDA = BK + 8;
    constexpr int T = 2 * BN;
    __shared__ unsigned short As[BM * LDA];
    __shared__ unsigned short Bs[BN * LDA];
    int tid = threadIdx.x;
    int m0 = blockIdx.y * BM, n0 = blockIdx.x * BN;
    int wave = tid >> 6, lane = tid & 63;
    int wm = wave & 1, wn = wave >> 1;
    int mlane = lane & 15, kgrp = lane >> 4;

    floatx4 acc[4][4];
    #pragma unroll
    for (int i = 0; i < 4; i++)
        #pragma unroll
        for (int j = 0; j < 4; j++) acc[i][j] = (floatx4){0.f, 0.f, 0.f, 0.f};

    for (int k0 = 0; k0 < K; k0 += BK) {
        #pragma unroll
        for (int c = tid; c < 512; c += T) {
            int r = c >> 2, cb = (c & 3) * 8;
            int rg = m0 + r;
            short8 v;
            if (rg < M) v = *(const short8*)(A + (size_t)rg * K + k0 + cb);
            else        v = (short8){0, 0, 0, 0, 0, 0, 0, 0};
            *(short8*)&As[r * LDA + cb] = v;
        }
        #pragma unroll
        for (int c = tid; c < BN * 4; c += T) {
            int r = c >> 2, cb = (c & 3) * 8;
            short8 w = *(const short8*)(Bt + (size_t)(n0 + r) * K + k0 + cb);
            *(short8*)&Bs[r * LDA + cb] = w;
        }
        __syncthreads();
        short8 af[4], bfr[4];
        #pragma unroll
        for (int mt = 0; mt < 4; mt++)
            af[mt] = *(const short8*)&As[(wm * 64 + mt * 16 + mlane) * LDA + kgrp * 8];
        #pragma unroll
        for (int nt = 0; nt < 4; nt++)
            bfr[nt] = *(const short8*)&Bs[(wn * 64 + nt * 16 + mlane) * LDA + kgrp * 8];
        #pragma unroll
        for (int mt = 0; mt < 4; mt++)
            #pragma unroll
            for (int nt = 0; nt < 4; nt++)
                acc[mt][nt] = __builtin_amdgcn_mfma_f32_16x16x32_bf16(af[mt], bfr[nt],
                                                                      acc[mt][nt], 0, 0, 0);
        __syncthreads();
    }
    #pragma unroll
    for (int mt = 0; mt < 4; mt++) {
        #pragma unroll
        for (int nt = 0; nt < 4; nt++) {
            int col = n0 + wn * 64 + nt * 16 + mlane;
            float bv = bias ? bias[col] : 0.f;
            #pragma unroll
            for (int r = 0; r < 4; r++) {
                int row = m0 + wm * 64 + mt * 16 + kgrp * 4 + r;
                if (row < M) {
                    float v = acc[mt][nt][r] + bv;
                    if (doRelu) v = fmaxf(v, 0.f);
                    storeC(C + (size_t)row * N + col, v);
                }
            }
        }
    }
}

// ---------------- launch ----------------

extern "C" void kernel_launch(void* const* d_in, const int* in_sizes, int n_in,
                              void* d_out, int out_size, void* d_ws, size_t ws_size,
                              hipStream_t stream) {
    const float* x   = (const float*)d_in[0];
    const int*   src = (const int*)d_in[1];
    const int*   dst = (const int*)d_in[2];
    const float* W1 = (const float*)d_in[3];
    const float* b1 = (const float*)d_in[4];
    const float* W2 = (const float*)d_in[5];
    const float* b2 = (const float*)d_in[6];
    const float* W3 = (const float*)d_in[7];
    const float* b3 = (const float*)d_in[8];
    float* out = (float*)d_out;

    char* ws = (char*)d_ws;
    size_t o = 0;
    auto alloc = [&](size_t bytes) -> char* {
        char* p = ws + o;
        o = (o + bytes + 255) & ~(size_t)255;
        return p;
    };
    int* off     = (int*)alloc((size_t)(N_NODES + 1) * 4);
    int* cur     = (int*)alloc((size_t)N_NODES * 4);
    int* csr     = (int*)alloc((size_t)N_EDGES * 4);
    int* partial = (int*)alloc((size_t)N_NODES * 4);
    int* bsum    = (int*)alloc(256 * 4);
    unsigned short* Wt1 = (unsigned short*)alloc((size_t)128 * 256 * 2);
    unsigned short* Wt2 = (unsigned short*)alloc((size_t)256 * 256 * 2);
    unsigned short* Wt3 = (unsigned short*)alloc((size_t)256 * 128 * 2);
    char* R1 = alloc((size_t)N_NODES * 256 * 2);
    char* R2 = alloc((size_t)N_NODES * 256 * 2);
    char* R3 = alloc((size_t)N_NODES * 256 * 2);

    unsigned short* xb    = (unsigned short*)R1;  // 50000x128 bf16
    unsigned short* aggX  = (unsigned short*)R2;  // 50000x128 bf16
    unsigned short* h1    = (unsigned short*)R3;  // 50000x256 bf16
    unsigned short* agg2o = (unsigned short*)R1;  // 50000x256 bf16
    unsigned short* h2    = (unsigned short*)R2;  // 50000x256 bf16
    unsigned short* t     = (unsigned short*)R3;  // 50000x128 bf16
    float*          pmean = (float*)R1;           // 12500x128 fp32 partial means

    const int nb = (N_NODES + 255) / 256;  // 196

    hipMemsetAsync(cur, 0, (size_t)N_NODES * 4, stream);
    const int hpThreads = N_EDGES + 131072 + N_NODES * 128 / 4;
    histprep_kernel<<<(hpThreads + 255) / 256, 256, 0, stream>>>(dst, cur, W1, W2, W3, x,
                                                                 Wt1, Wt2, Wt3, xb);
    scan_block_kernel<<<nb, 256, 0, stream>>>(cur, partial, bsum, N_NODES);
    finalize_kernel<<<nb, 256, 0, stream>>>(partial, bsum, cur, off, N_NODES);
    fill_kernel<<<(N_EDGES + 255) / 256, 256, 0, stream>>>(src, dst, cur, csr, N_EDGES);

    const int mb = (N_NODES + 127) / 128;  // 391

    // Layer 1
    agg128_kernel<<<N_NODES / 4, 256, 0, stream>>>(xb, off, csr, aggX);
    gemm_bf16_kernel<256, unsigned short><<<dim3(1, mb), 512, 0, stream>>>(aggX, Wt1, b1, h1,
                                                                           N_NODES, 128, 256, 1);
    // Layer 2
    agg256_kernel<<<N_NODES / 4, 256, 0, stream>>>(h1, off, csr, agg2o);
    gemm_bf16_kernel<256, unsigned short><<<dim3(1, mb), 512, 0, stream>>>(agg2o, Wt2, b2, h2,
                                                                           N_NODES, 256, 256, 1);
    // Layer 3 reordered: t = h2 @ W3 (bf16), then fused agg+bias+relu+partial-mean
    gemm_bf16_kernel<128, unsigned short><<<dim3(1, mb), 256, 0, stream>>>(h2, Wt3, nullptr, t,
                                                                           N_NODES, 256, 128, 0);
    agg3_mean_kernel<<<N_NODES / 4, 256, 0, stream>>>(t, off, csr, b3, pmean);

    hipMemsetAsync(out, 0, 128 * 4, stream);
    mean_reduce_kernel<<<128, 256, 0, stream>>>(pmean, out, N_NODES / 4);
}